// Round 1
// baseline (709.194 us; speedup 1.0000x reference)
//
#include <hip/hip_runtime.h>
#include <hip/hip_bf16.h>
#include <math.h>

// Problem constants
#define B_   8
#define T_   128
#define D_   512
#define M_   2048
#define HID_ 128
#define BT_  1024   // B*T

// ws layout (float offsets)
#define OFF_SCAL   0L
#define OFF_WQKV   16L
#define OFF_QKV    (OFF_WQKV + 786432L)          // 1024*1536
#define OFF_QC     (OFF_QKV + 1572864L)
#define OFF_QS     (OFF_QC + 524288L)
#define OFF_KC     (OFF_QS + 524288L)
#define OFF_KS     (OFF_KC + 524288L)
#define OFF_SK     (OFF_KS + 524288L)            // [Qre|Qim|dKre|dKim] each BT*M
#define OFF_KP     (OFF_SK + 4L*BT_*M_)          // [KR|KI] each BT*M (exclusive prefix)
#define OFF_PSI    (OFF_KP + 2L*BT_*M_)
#define OFF_SCORES (OFF_PSI + 1L*BT_*M_)         // B*T*T
#define OFF_HIDACC (OFF_SCORES + 131072L)
#define OFF_HID    (OFF_HIDACC + 131072L)
#define OFF_HFEAT  (OFF_HID + 131072L)
#define OFF_VRAW   (OFF_HFEAT + 524288L)
#define OFF_VLN    (OFF_VRAW + 524288L)
#define OFF_V1     (OFF_VLN + 524288L)
#define OFF_VF     (OFF_V1 + 524288L)

#define FLAG_BIAS     1
#define FLAG_GELU     2
#define FLAG_ROWSCALE 4
#define FLAG_ATOMIC   8
#define FLAG_MASK     16
#define FLAG_TWOPROD  32

__device__ __forceinline__ float gelu_f(float x) {
    return 0.5f * x * (1.0f + erff(x * 0.70710678118654752440f));
}

__global__ void scal_kernel(const float* tq, const float* tk, const float* om,
                            const float* gf, const float* gv, float* scal) {
    if (threadIdx.x == 0) {
        scal[0] = 0.5f * tanhf(tq[0]);
        scal[1] = 0.5f * tanhf(tk[0]);
        scal[2] = 0.5f * tanhf(om[0]);
        scal[3] = 0.25f / (1.0f + expf(-gf[0]));
        scal[4] = 0.25f / (1.0f + expf(-gv[0]));
    }
}

__global__ __launch_bounds__(256) void wcopy_kernel(const float* __restrict__ Wq,
                                                    const float* __restrict__ Wk,
                                                    const float* __restrict__ Wv,
                                                    float* __restrict__ Wqkv) {
    int idx = blockIdx.x * 256 + threadIdx.x;   // 512*512
    if (idx >= 512 * 512) return;
    int r = idx >> 9, c = idx & 511;
    Wqkv[r * 1536 + c]        = Wq[idx];
    Wqkv[r * 1536 + 512 + c]  = Wk[idx];
    Wqkv[r * 1536 + 1024 + c] = Wv[idx];
}

// qc = q*cos(ph_q)*sign, qs = q*sin(ph_q)*sign; likewise kc,ks (sign folded in)
__global__ __launch_bounds__(256) void phase_kernel(const float* __restrict__ qkv,
                                                    const float* __restrict__ sign,
                                                    const float* __restrict__ scal,
                                                    float* __restrict__ qc, float* __restrict__ qs,
                                                    float* __restrict__ kc, float* __restrict__ ks) {
    int idx = blockIdx.x * 256 + threadIdx.x;   // BT*D
    if (idx >= BT_ * D_) return;
    int d = idx & 511;
    int bt = idx >> 9;
    int t = bt & 127;
    float q = qkv[(long)bt * 1536 + d];
    float k = qkv[(long)bt * 1536 + 512 + d];
    float thq = scal[0], thk = scal[1], omg = scal[2];
    float sg = sign[d];
    float ft = (float)t;
    float phq = thq * q - omg * ft;
    float phk = thk * k + omg * ft;
    qc[idx] = q * cosf(phq) * sg;
    qs[idx] = q * sinf(phq) * sg;
    kc[idx] = k * cosf(phk) * sg;
    ks[idx] = k * sinf(phk) * sg;
}

// Dense sketches (B*T, M) for Qre,Qim,dKre,dKim via LDS scatter-accumulate
__global__ __launch_bounds__(256) void sketch_kernel(const float* __restrict__ qc,
                                                     const float* __restrict__ qs,
                                                     const float* __restrict__ kc,
                                                     const float* __restrict__ ks,
                                                     const int* __restrict__ h,
                                                     float* __restrict__ SK) {
    int bt = blockIdx.x;
    int tid = threadIdx.x;
    __shared__ float s0[M_], s1[M_], s2[M_], s3[M_];   // 32 KB
    for (int j = tid; j < M_; j += 256) { s0[j] = 0.f; s1[j] = 0.f; s2[j] = 0.f; s3[j] = 0.f; }
    __syncthreads();
    for (int i = tid; i < D_; i += 256) {
        int m = h[i];
        long base = (long)bt * D_ + i;
        atomicAdd(&s0[m], qc[base]);
        atomicAdd(&s1[m], qs[base]);
        atomicAdd(&s2[m], kc[base]);
        atomicAdd(&s3[m], ks[base]);
    }
    __syncthreads();
    long ob = (long)bt * M_;
    for (int j = tid; j < M_; j += 256) {
        SK[ob + j]                  = s0[j];
        SK[1L * BT_ * M_ + ob + j]  = s1[j];
        SK[2L * BT_ * M_ + ob + j]  = s2[j];
        SK[3L * BT_ * M_ + ob + j]  = s3[j];
    }
}

// Exclusive prefix over t of dK sketches -> KP; inclusive total -> Kf (d_out)
__global__ __launch_bounds__(256) void prefix_kernel(const float* __restrict__ SK,
                                                     float* __restrict__ KP,
                                                     float* __restrict__ kf_out) {
    int idx = blockIdx.x * 256 + threadIdx.x;   // 2*B*M
    if (idx >= 2 * B_ * M_) return;
    int m = idx & (M_ - 1);
    int bm = idx >> 11;
    int b = bm & 7;
    int comp = bm >> 3;
    const float* src = SK + (2L + comp) * BT_ * M_ + (long)b * T_ * M_ + m;
    float* dst = KP + (long)comp * BT_ * M_ + (long)b * T_ * M_ + m;
    float acc = 0.f;
    for (int t = 0; t < T_; ++t) {
        dst[(long)t * M_] = acc;
        acc += src[(long)t * M_];
    }
    kf_out[((long)b * 2 + comp) * M_ + m] = acc;
}

// psi[b,t,n] = (sum_i qc_i*KR[(n-h_i)&2047] - qs_i*KI[(n-h_i)&2047]) * rsqrt(M*(t+1))
__global__ __launch_bounds__(256) void psi_kernel(const float* __restrict__ KP,
                                                  const float* __restrict__ qc,
                                                  const float* __restrict__ qs,
                                                  const int* __restrict__ h,
                                                  float* __restrict__ psi) {
    int bt = blockIdx.x;
    int tid = threadIdx.x;
    int t = bt & 127;
    __shared__ float KRs[2 * M_];   // duplicated to avoid mod in inner loop
    __shared__ float KIs[2 * M_];
    __shared__ float qcs[D_], qss[D_];
    __shared__ int hs[D_];
    for (int j = tid; j < M_; j += 256) {
        float vr = KP[(long)bt * M_ + j];
        float vi = KP[1L * BT_ * M_ + (long)bt * M_ + j];
        KRs[j] = vr; KRs[j + M_] = vr;
        KIs[j] = vi; KIs[j + M_] = vi;
    }
    for (int i = tid; i < D_; i += 256) {
        qcs[i] = qc[(long)bt * D_ + i];
        qss[i] = qs[(long)bt * D_ + i];
        hs[i] = h[i];
    }
    __syncthreads();
    float acc[8] = {0.f, 0.f, 0.f, 0.f, 0.f, 0.f, 0.f, 0.f};
    for (int i = 0; i < D_; ++i) {
        float qcv = qcs[i], qsv = qss[i];
        int base = (tid - hs[i]) & (M_ - 1);
        #pragma unroll
        for (int j = 0; j < 8; ++j) {
            int idx = base + j * 256;   // < 4096, duplicated buffer
            acc[j] += qcv * KRs[idx] - qsv * KIs[idx];
        }
    }
    float scale = rsqrtf((float)M_ * (float)(t + 1));
    #pragma unroll
    for (int j = 0; j < 8; ++j)
        psi[(long)bt * M_ + tid + j * 256] = acc[j] * scale;
}

// Generic stride-flexible fp32 tiled GEMM. C[i,j] (+)= alpha * sum_k A[i,k]*B[k,j] (- A2*B2)
template<int BM, int BN, int BK, int FLAGS>
__global__ __launch_bounds__(256) void gemm_kernel(
    const float* __restrict__ A, const float* __restrict__ Bm,
    const float* __restrict__ bias, float* __restrict__ C,
    int Md, int Nd, int Kd,
    long sa_i, long sa_k, long sb_k, long sb_j, long sc_i,
    long abz, long bbz, long cbz,
    int splitk, float alpha, long aoff2, long boff2)
{
    constexpr int TM = BM / 16, TN = BN / 16;
    constexpr bool TP = (FLAGS & FLAG_TWOPROD) != 0;
    __shared__ float As[BK][BM + 4];
    __shared__ float Bs[BK][BN + 4];
    __shared__ float As2[TP ? BK : 1][TP ? (BM + 4) : 1];
    __shared__ float Bs2[TP ? BK : 1][TP ? (BN + 4) : 1];

    int bz = blockIdx.z;
    int batch = bz / splitk, kslice = bz % splitk;
    const float* Ab = A + (long)batch * abz;
    const float* Bb = Bm + (long)batch * bbz;
    float* Cb = C + (long)batch * cbz;
    int row0 = blockIdx.y * BM, col0 = blockIdx.x * BN;
    int tid = threadIdx.x, tx = tid & 15, ty = tid >> 4;

    float acc[TM][TN] = {};
    int klen = (Kd + splitk - 1) / splitk;
    int k0 = kslice * klen, k1 = min(Kd, k0 + klen);

    for (int kt = k0; kt < k1; kt += BK) {
        for (int p = tid; p < BM * BK; p += 256) {
            int i, kk;
            if (sa_k == 1) { kk = p % BK; i = p / BK; } else { i = p % BM; kk = p / BM; }
            int gi = row0 + i, gk = kt + kk;
            float v = 0.f, v2 = 0.f;
            if (gi < Md && gk < k1) {
                long off = (long)gi * sa_i + (long)gk * sa_k;
                v = Ab[off];
                if constexpr (TP) v2 = Ab[off + aoff2];
            }
            As[kk][i] = v;
            if constexpr (TP) As2[kk][i] = v2;
        }
        for (int p = tid; p < BN * BK; p += 256) {
            int j, kk;
            if (sb_j == 1) { j = p % BN; kk = p / BN; } else { kk = p % BK; j = p / BK; }
            int gj = col0 + j, gk = kt + kk;
            float v = 0.f, v2 = 0.f;
            if (gj < Nd && gk < k1) {
                long off = (long)gk * sb_k + (long)gj * sb_j;
                v = Bb[off];
                if constexpr (TP) v2 = Bb[off + boff2];
            }
            Bs[kk][j] = v;
            if constexpr (TP) Bs2[kk][j] = v2;
        }
        __syncthreads();
        #pragma unroll
        for (int kk = 0; kk < BK; ++kk) {
            float a[TM], b[TN];
            #pragma unroll
            for (int r = 0; r < TM; ++r) a[r] = As[kk][ty * TM + r];
            #pragma unroll
            for (int c = 0; c < TN; ++c) b[c] = Bs[kk][tx * TN + c];
            #pragma unroll
            for (int r = 0; r < TM; ++r)
                #pragma unroll
                for (int c = 0; c < TN; ++c)
                    acc[r][c] += a[r] * b[c];
            if constexpr (TP) {
                float a2[TM], b2[TN];
                #pragma unroll
                for (int r = 0; r < TM; ++r) a2[r] = As2[kk][ty * TM + r];
                #pragma unroll
                for (int c = 0; c < TN; ++c) b2[c] = Bs2[kk][tx * TN + c];
                #pragma unroll
                for (int r = 0; r < TM; ++r)
                    #pragma unroll
                    for (int c = 0; c < TN; ++c)
                        acc[r][c] -= a2[r] * b2[c];
            }
        }
        __syncthreads();
    }

    #pragma unroll
    for (int r = 0; r < TM; ++r) {
        int gi = row0 + ty * TM + r;
        if (gi >= Md) continue;
        #pragma unroll
        for (int c = 0; c < TN; ++c) {
            int gj = col0 + tx * TN + c;
            if (gj >= Nd) continue;
            if (FLAGS & FLAG_MASK) { if (gj >= gi) continue; }   // strict tau < t
            float v = acc[r][c] * alpha;
            if (FLAGS & FLAG_ATOMIC) {
                atomicAdd(&Cb[(long)gi * sc_i + gj], v);
            } else {
                if (FLAGS & FLAG_BIAS) v += bias[gj];
                if (FLAGS & FLAG_GELU) v = gelu_f(v);
                if (FLAGS & FLAG_ROWSCALE) v *= rsqrtf((float)(gi & 127) + 1.0f);
                Cb[(long)gi * sc_i + gj] = v;
            }
        }
    }
}

__global__ __launch_bounds__(256) void biasgelu_kernel(const float* __restrict__ acc,
                                                       const float* __restrict__ bias,
                                                       float* __restrict__ out, int n, int nb) {
    int idx = blockIdx.x * 256 + threadIdx.x;
    if (idx >= n) return;
    out[idx] = gelu_f(acc[idx] + bias[idx % nb]);
}

// LN over D=512. FINAL=0: out = LN(x1)*g+b. FINAL=1: out = LN(x1 + gf*x2 + gv*x3)*g+b
template<int FINAL>
__global__ __launch_bounds__(256) void ln_kernel(const float* __restrict__ x1,
                                                 const float* __restrict__ x2,
                                                 const float* __restrict__ x3,
                                                 const float* __restrict__ g,
                                                 const float* __restrict__ bb,
                                                 const float* __restrict__ scal,
                                                 float* __restrict__ out) {
    int row = blockIdx.x, tid = threadIdx.x;
    long base = (long)row * D_;
    int d0 = tid, d1 = tid + 256;
    float v0, v1;
    if (FINAL) {
        float gf = scal[3], gv = scal[4];
        v0 = x1[base + d0] + gf * x2[base + d0] + gv * x3[base + d0];
        v1 = x1[base + d1] + gf * x2[base + d1] + gv * x3[base + d1];
    } else {
        v0 = x1[base + d0];
        v1 = x1[base + d1];
    }
    float s = v0 + v1;
    #pragma unroll
    for (int o = 32; o > 0; o >>= 1) s += __shfl_down(s, o);
    __shared__ float red[8];
    int wid = tid >> 6, lane = tid & 63;
    if (lane == 0) red[wid] = s;
    __syncthreads();
    float mu = (red[0] + red[1] + red[2] + red[3]) * (1.0f / D_);
    float e0 = v0 - mu, e1 = v1 - mu;
    float sq = e0 * e0 + e1 * e1;
    #pragma unroll
    for (int o = 32; o > 0; o >>= 1) sq += __shfl_down(sq, o);
    if (lane == 0) red[4 + wid] = sq;
    __syncthreads();
    float var = (red[4] + red[5] + red[6] + red[7]) * (1.0f / D_);
    float rs = rsqrtf(var + 1e-5f);
    out[base + d0] = e0 * rs * g[d0] + bb[d0];
    out[base + d1] = e1 * rs * g[d1] + bb[d1];
}

extern "C" void kernel_launch(void* const* d_in, const int* in_sizes, int n_in,
                              void* d_out, int out_size, void* d_ws, size_t ws_size,
                              hipStream_t stream) {
    const float* e      = (const float*)d_in[0];
    const int*   h      = (const int*)d_in[1];
    const float* sign   = (const float*)d_in[2];
    const float* Wq     = (const float*)d_in[3];
    const float* Wk     = (const float*)d_in[4];
    const float* Wv     = (const float*)d_in[5];
    const float* ro_w1  = (const float*)d_in[6];
    const float* ro_b1  = (const float*)d_in[7];
    const float* ro_w2  = (const float*)d_in[8];
    const float* ro_b2  = (const float*)d_in[9];
    const float* vp_ln_g= (const float*)d_in[10];
    const float* vp_ln_b= (const float*)d_in[11];
    const float* vp_w1  = (const float*)d_in[12];
    const float* vp_b1  = (const float*)d_in[13];
    const float* vp_w2  = (const float*)d_in[14];
    const float* vp_b2  = (const float*)d_in[15];
    const float* ln_g   = (const float*)d_in[16];
    const float* ln_b   = (const float*)d_in[17];
    const float* tq     = (const float*)d_in[18];
    const float* tk     = (const float*)d_in[19];
    const float* om     = (const float*)d_in[20];
    const float* gfr    = (const float*)d_in[21];
    const float* gvr    = (const float*)d_in[22];

    float* ws     = (float*)d_ws;
    float* scal   = ws + OFF_SCAL;
    float* wqkv   = ws + OFF_WQKV;
    float* qkv    = ws + OFF_QKV;
    float* qc     = ws + OFF_QC;
    float* qs     = ws + OFF_QS;
    float* kc     = ws + OFF_KC;
    float* ks     = ws + OFF_KS;
    float* sk     = ws + OFF_SK;
    float* kp     = ws + OFF_KP;
    float* psi    = ws + OFF_PSI;
    float* scores = ws + OFF_SCORES;
    float* hidacc = ws + OFF_HIDACC;
    float* hid    = ws + OFF_HID;
    float* hfeat  = ws + OFF_HFEAT;
    float* vraw   = ws + OFF_VRAW;
    float* vln    = ws + OFF_VLN;
    float* v1     = ws + OFF_V1;
    float* vf     = ws + OFF_VF;

    float* ys = (float*)d_out;
    float* kf = ys + (long)BT_ * D_;
    float* hf = kf + (long)B_ * 2 * M_;

    scal_kernel<<<1, 64, 0, stream>>>(tq, tk, om, gfr, gvr, scal);
    wcopy_kernel<<<1024, 256, 0, stream>>>(Wq, Wk, Wv, wqkv);

    // qkv = e @ [Wq|Wk|Wv]  (1024 x 1536 x 512)
    gemm_kernel<64, 64, 16, 0><<<dim3(24, 16, 1), 256, 0, stream>>>(
        e, wqkv, nullptr, qkv, 1024, 1536, 512,
        512, 1, 1536, 1, 1536, 0, 0, 0, 1, 1.0f, 0, 0);

    phase_kernel<<<2048, 256, 0, stream>>>(qkv, sign, scal, qc, qs, kc, ks);
    sketch_kernel<<<1024, 256, 0, stream>>>(qc, qs, kc, ks, h, sk);
    prefix_kernel<<<128, 256, 0, stream>>>(sk, kp, kf);
    psi_kernel<<<1024, 256, 0, stream>>>(kp, qc, qs, h, psi);

    hipMemsetAsync(scores, 0, (size_t)B_ * T_ * T_ * 4, stream);
    hipMemsetAsync(hidacc, 0, (size_t)BT_ * HID_ * 4, stream);

    // A[b,t,tau] = <Qre_t, dKre_tau> - <Qim_t, dKim_tau>, strict tau<t (128x128x2048, b=8, splitk=4)
    gemm_kernel<32, 32, 32, FLAG_TWOPROD | FLAG_MASK | FLAG_ATOMIC><<<dim3(4, 4, 32), 256, 0, stream>>>(
        sk, sk + 2L * BT_ * M_, nullptr, scores, 128, 128, 2048,
        (long)M_, 1, 1, (long)M_, 128,
        (long)T_ * M_, (long)T_ * M_, (long)T_ * T_,
        4, 1.0f, (long)BT_ * M_, (long)BT_ * M_);

    // vraw[b,t,d] = (A @ v) * rsqrt(t+1)   (128x512x128, b=8)
    gemm_kernel<32, 64, 32, FLAG_ROWSCALE><<<dim3(8, 4, 8), 256, 0, stream>>>(
        scores, qkv + 1024, nullptr, vraw, 128, 512, 128,
        128, 1, 1536, 1, 512,
        (long)T_ * T_, (long)T_ * 1536, (long)T_ * D_,
        1, 1.0f, 0, 0);

    ln_kernel<0><<<1024, 256, 0, stream>>>(vraw, nullptr, nullptr, vp_ln_g, vp_ln_b, scal, vln);

    // v1 = gelu(vln @ vp_w1 + vp_b1); vf = v1 @ vp_w2 + vp_b2
    gemm_kernel<32, 64, 32, FLAG_BIAS | FLAG_GELU><<<dim3(8, 32, 1), 256, 0, stream>>>(
        vln, vp_w1, vp_b1, v1, 1024, 512, 512,
        512, 1, 512, 1, 512, 0, 0, 0, 1, 1.0f, 0, 0);
    gemm_kernel<32, 64, 32, FLAG_BIAS><<<dim3(8, 32, 1), 256, 0, stream>>>(
        v1, vp_w2, vp_b2, vf, 1024, 512, 512,
        512, 1, 512, 1, 512, 0, 0, 0, 1, 1.0f, 0, 0);

    // hidacc = psi @ ro_w1 (1024x128x2048, splitk=4, atomic); hid = gelu(hidacc + ro_b1)
    gemm_kernel<32, 32, 32, FLAG_ATOMIC><<<dim3(4, 32, 4), 256, 0, stream>>>(
        psi, ro_w1, nullptr, hidacc, 1024, 128, 2048,
        (long)M_, 1, 128, 1, 128, 0, 0, 0, 4, 1.0f, 0, 0);
    biasgelu_kernel<<<512, 256, 0, stream>>>(hidacc, ro_b1, hid, BT_ * HID_, HID_);

    // hfeat = hid @ ro_w2 + ro_b2 (1024x512x128)
    gemm_kernel<32, 64, 32, FLAG_BIAS><<<dim3(8, 32, 1), 256, 0, stream>>>(
        hid, ro_w2, ro_b2, hfeat, 1024, 512, 128,
        128, 1, 512, 1, 512, 0, 0, 0, 1, 1.0f, 0, 0);

    // ys = LN(e + gf*hfeat + gv*vf)
    ln_kernel<1><<<1024, 256, 0, stream>>>(e, hfeat, vf, ln_g, ln_b, scal, ys);

    // Hf[b,c,d,m] = sum_tau v[b,tau,d]*dK_c[b,tau,m]  (512x2048x128 per (b,c))
    gemm_kernel<64, 64, 16, 0><<<dim3(32, 8, 8), 256, 0, stream>>>(
        qkv + 1024, sk + 2L * BT_ * M_, nullptr, hf, 512, 2048, 128,
        1, 1536, (long)M_, 1, (long)M_,
        (long)T_ * 1536, (long)T_ * M_, 2L * D_ * M_,
        1, 1.0f, 0, 0);
    gemm_kernel<64, 64, 16, 0><<<dim3(32, 8, 8), 256, 0, stream>>>(
        qkv + 1024, sk + 3L * BT_ * M_, nullptr, hf + (long)D_ * M_, 512, 2048, 128,
        1, 1536, (long)M_, 1, (long)M_,
        (long)T_ * 1536, (long)T_ * M_, 2L * D_ * M_,
        1, 1.0f, 0, 0);
}

// Round 2
// 369.244 us; speedup vs baseline: 1.9207x; 1.9207x over previous
//
#include <hip/hip_runtime.h>
#include <hip/hip_bf16.h>
#include <math.h>

#define B_   8
#define T_   128
#define D_   512
#define M_   2048
#define HID_ 128
#define BT_  1024

typedef __attribute__((ext_vector_type(8))) short short8t;
typedef __attribute__((ext_vector_type(4))) float f32x4;
typedef __hip_bfloat16 bf16;

// ws layout (float offsets; all multiples of 16 -> 64B aligned)
#define OFF_SCAL   0L
#define OFF_QKV    16L                            // 1024*1536 f32
#define OFF_QC     (OFF_QKV + 1572864L)
#define OFF_QS     (OFF_QC + 524288L)
#define OFF_KC     (OFF_QS + 524288L)
#define OFF_KS     (OFF_KC + 524288L)
#define OFF_SK2    (OFF_KS + 524288L)             // [dKre|dKim] f32, 2*BT*M
#define OFF_KP     (OFF_SK2 + 4194304L)           // [KR|KI] f32 prefix
#define OFF_VRAW   (OFF_KP + 4194304L)
#define OFF_VF     (OFF_VRAW + 524288L)
#define OFF_HFEAT  (OFF_VF + 524288L)
// bf16 buffers (size in floats = elems/2)
#define OFF_EB     (OFF_HFEAT + 524288L)          // 1024x512
#define OFF_WQKVT  (OFF_EB + 262144L)             // 1536x512
#define OFF_VP1T   (OFF_WQKVT + 393216L)          // 512x512
#define OFF_VP2T   (OFF_VP1T + 131072L)
#define OFF_RO1T   (OFF_VP2T + 131072L)           // 128x2048
#define OFF_RO2T   (OFF_RO1T + 131072L)           // 512x128
#define OFF_QCAT   (OFF_RO2T + 32768L)            // 1024x4096
#define OFF_KCAT   (OFF_QCAT + 2097152L)          // 1024x4096
#define OFF_DKT    (OFF_KCAT + 2097152L)          // 2x8x2048x128
#define OFF_VTB    (OFF_DKT + 2097152L)           // 8x512x128
#define OFF_PSIB   (OFF_VTB + 262144L)            // 1024x2048
#define OFF_SCOB   (OFF_PSIB + 1048576L)          // 8x128x128
#define OFF_VLNB   (OFF_SCOB + 65536L)            // 1024x512
#define OFF_V1B    (OFF_VLNB + 262144L)           // 1024x512
#define OFF_HIDB   (OFF_V1B + 262144L)            // 1024x128

#define FLAG_BIAS     1
#define FLAG_GELU     2
#define FLAG_ROWSCALE 4
#define FLAG_MASK     16

__device__ __forceinline__ float gelu_f(float x) {
    return 0.5f * x * (1.0f + erff(x * 0.70710678118654752440f));
}

__global__ void scal_kernel(const float* tq, const float* tk, const float* om,
                            const float* gf, const float* gv, float* scal) {
    if (threadIdx.x == 0) {
        scal[0] = 0.5f * tanhf(tq[0]);
        scal[1] = 0.5f * tanhf(tk[0]);
        scal[2] = 0.5f * tanhf(om[0]);
        scal[3] = 0.25f / (1.0f + expf(-gf[0]));
        scal[4] = 0.25f / (1.0f + expf(-gv[0]));
    }
}

__global__ __launch_bounds__(256) void cast_kernel(const float* __restrict__ in,
                                                   bf16* __restrict__ out, int n) {
    int i = blockIdx.x * 256 + threadIdx.x;
    if (i < n) out[i] = __float2bfloat16(in[i]);
}

// tiled transpose-cast: in f32 [R][C] (ld_in, batch bs_in) -> out bf16 [C][R] (batch bs_out)
__global__ __launch_bounds__(256) void castT_kernel(const float* __restrict__ in,
                                                    bf16* __restrict__ out,
                                                    int R, int C, int ld_in,
                                                    long bs_in, long bs_out) {
    __shared__ float tile[32][33];
    int b = blockIdx.z;
    int c0 = blockIdx.x * 32, r0 = blockIdx.y * 32;
    int tx = threadIdx.x & 31, ty = threadIdx.x >> 5;
    for (int rr = ty; rr < 32; rr += 8) {
        int r = r0 + rr, c = c0 + tx;
        tile[rr][tx] = (r < R && c < C) ? in[(long)b * bs_in + (long)r * ld_in + c] : 0.f;
    }
    __syncthreads();
    for (int cc = ty; cc < 32; cc += 8) {
        int c = c0 + cc, r = r0 + tx;
        if (c < C && r < R) out[(long)b * bs_out + (long)c * R + r] = __float2bfloat16(tile[tx][cc]);
    }
}

__global__ __launch_bounds__(256) void phase_kernel(const float* __restrict__ qkv,
                                                    const float* __restrict__ sign,
                                                    const float* __restrict__ scal,
                                                    float* __restrict__ qc, float* __restrict__ qs,
                                                    float* __restrict__ kc, float* __restrict__ ks) {
    int idx = blockIdx.x * 256 + threadIdx.x;
    if (idx >= BT_ * D_) return;
    int d = idx & 511;
    int bt = idx >> 9;
    int t = bt & 127;
    float q = qkv[(long)bt * 1536 + d];
    float k = qkv[(long)bt * 1536 + 512 + d];
    float thq = scal[0], thk = scal[1], omg = scal[2];
    float sg = sign[d];
    float ft = (float)t;
    float phq = thq * q - omg * ft;
    float phk = thk * k + omg * ft;
    qc[idx] = q * cosf(phq) * sg;
    qs[idx] = q * sinf(phq) * sg;
    kc[idx] = k * cosf(phk) * sg;
    ks[idx] = k * sinf(phk) * sg;
}

// sketches: SK2 f32 = [dKre|dKim]; qcat bf16 = [Qre|Qim]; kcat bf16 = [dKre|-dKim]
__global__ __launch_bounds__(256) void sketch_kernel(const float* __restrict__ qc,
                                                     const float* __restrict__ qs,
                                                     const float* __restrict__ kc,
                                                     const float* __restrict__ ks,
                                                     const int* __restrict__ h,
                                                     float* __restrict__ SK2,
                                                     bf16* __restrict__ qcat,
                                                     bf16* __restrict__ kcat) {
    int bt = blockIdx.x;
    int tid = threadIdx.x;
    __shared__ float s0[M_], s1[M_], s2[M_], s3[M_];
    for (int j = tid; j < M_; j += 256) { s0[j] = 0.f; s1[j] = 0.f; s2[j] = 0.f; s3[j] = 0.f; }
    __syncthreads();
    for (int i = tid; i < D_; i += 256) {
        int m = h[i];
        long base = (long)bt * D_ + i;
        atomicAdd(&s0[m], qc[base]);
        atomicAdd(&s1[m], qs[base]);
        atomicAdd(&s2[m], kc[base]);
        atomicAdd(&s3[m], ks[base]);
    }
    __syncthreads();
    long ob = (long)bt * M_;
    long qb = (long)bt * 4096;
    for (int j = tid; j < M_; j += 256) {
        SK2[ob + j]                 = s2[j];
        SK2[(long)BT_ * M_ + ob + j] = s3[j];
        qcat[qb + j]        = __float2bfloat16(s0[j]);
        qcat[qb + 2048 + j] = __float2bfloat16(s1[j]);
        kcat[qb + j]        = __float2bfloat16(s2[j]);
        kcat[qb + 2048 + j] = __float2bfloat16(-s3[j]);
    }
}

// exclusive prefix over t of SK2 -> KP; totals -> kf_out
__global__ __launch_bounds__(256) void prefix_kernel(const float* __restrict__ SK2,
                                                     float* __restrict__ KP,
                                                     float* __restrict__ kf_out) {
    int idx = blockIdx.x * 256 + threadIdx.x;
    if (idx >= 2 * B_ * M_) return;
    int m = idx & (M_ - 1);
    int bm = idx >> 11;
    int b = bm & 7;
    int comp = bm >> 3;
    const float* src = SK2 + (long)comp * BT_ * M_ + (long)b * T_ * M_ + m;
    float* dst = KP + (long)comp * BT_ * M_ + (long)b * T_ * M_ + m;
    float acc = 0.f;
    for (int t = 0; t < T_; ++t) {
        dst[(long)t * M_] = acc;
        acc += src[(long)t * M_];
    }
    kf_out[((long)b * 2 + comp) * M_ + m] = acc;
}

// psi[b,t,n] -> bf16 out
__global__ __launch_bounds__(256) void psi_kernel(const float* __restrict__ KP,
                                                  const float* __restrict__ qc,
                                                  const float* __restrict__ qs,
                                                  const int* __restrict__ h,
                                                  bf16* __restrict__ psi_b) {
    int bt = blockIdx.x;
    int tid = threadIdx.x;
    int t = bt & 127;
    __shared__ float KRs[2 * M_];
    __shared__ float KIs[2 * M_];
    __shared__ float qcs[D_], qss[D_];
    __shared__ int hs[D_];
    for (int j = tid; j < M_; j += 256) {
        float vr = KP[(long)bt * M_ + j];
        float vi = KP[1L * BT_ * M_ + (long)bt * M_ + j];
        KRs[j] = vr; KRs[j + M_] = vr;
        KIs[j] = vi; KIs[j + M_] = vi;
    }
    for (int i = tid; i < D_; i += 256) {
        qcs[i] = qc[(long)bt * D_ + i];
        qss[i] = qs[(long)bt * D_ + i];
        hs[i] = h[i];
    }
    __syncthreads();
    float acc[8] = {0.f, 0.f, 0.f, 0.f, 0.f, 0.f, 0.f, 0.f};
    for (int i = 0; i < D_; ++i) {
        float qcv = qcs[i], qsv = qss[i];
        int base = (tid - hs[i]) & (M_ - 1);
        #pragma unroll
        for (int j = 0; j < 8; ++j) {
            int idx = base + j * 256;
            acc[j] += qcv * KRs[idx] - qsv * KIs[idx];
        }
    }
    float scale = rsqrtf((float)M_ * (float)(t + 1));
    #pragma unroll
    for (int j = 0; j < 8; ++j)
        psi_b[(long)bt * M_ + tid + j * 256] = __float2bfloat16(acc[j] * scale);
}

// MFMA bf16 TN GEMM: C[M,N] = A[M,K] * Bt[N,K]^T. 64x64 tile, 4 waves.
// Requires M%64==0 handled by grid, N%64==0, K%32==0, 16B-aligned buffers.
template<int FLAGS, int OUTB16>
__global__ __launch_bounds__(256) void gemm_mfma(
    const bf16* __restrict__ A, const bf16* __restrict__ Bt,
    const float* __restrict__ bias, void* __restrict__ Cv,
    int K, int ldc, long abz, long bbz, long cbz)
{
    __shared__ __align__(16) bf16 As[64][40];
    __shared__ __align__(16) bf16 Bs[64][40];
    int bz = blockIdx.z;
    const bf16* Ab = A + (long)bz * abz + (long)blockIdx.y * 64 * K;
    const bf16* Bb = Bt + (long)bz * bbz + (long)blockIdx.x * 64 * K;
    int tid = threadIdx.x;
    int lrow = tid >> 2;
    int lk = (tid & 3) * 8;
    int w = tid >> 6, lane = tid & 63;
    int wr = (w >> 1) * 32, wc = (w & 1) * 32;
    int fm = lane & 15, fk = (lane >> 4) * 8;
    f32x4 acc00 = {0.f,0.f,0.f,0.f}, acc01 = acc00, acc10 = acc00, acc11 = acc00;

    for (int kt = 0; kt < K; kt += 32) {
        *(float4*)&As[lrow][lk] = *(const float4*)&Ab[(long)lrow * K + kt + lk];
        *(float4*)&Bs[lrow][lk] = *(const float4*)&Bb[(long)lrow * K + kt + lk];
        __syncthreads();
        short8t a0 = *(const short8t*)&As[wr + fm][fk];
        short8t a1 = *(const short8t*)&As[wr + 16 + fm][fk];
        short8t b0 = *(const short8t*)&Bs[wc + fm][fk];
        short8t b1 = *(const short8t*)&Bs[wc + 16 + fm][fk];
        acc00 = __builtin_amdgcn_mfma_f32_16x16x32_bf16(a0, b0, acc00, 0, 0, 0);
        acc01 = __builtin_amdgcn_mfma_f32_16x16x32_bf16(a0, b1, acc01, 0, 0, 0);
        acc10 = __builtin_amdgcn_mfma_f32_16x16x32_bf16(a1, b0, acc10, 0, 0, 0);
        acc11 = __builtin_amdgcn_mfma_f32_16x16x32_bf16(a1, b1, acc11, 0, 0, 0);
        __syncthreads();
    }

    float* Cf = (float*)Cv;
    bf16* Cb = (bf16*)Cv;
    int row_base = blockIdx.y * 64 + wr + (lane >> 4) * 4;
    int col_base = blockIdx.x * 64 + wc + fm;
    #pragma unroll
    for (int fr = 0; fr < 2; ++fr) {
        #pragma unroll
        for (int fc = 0; fc < 2; ++fc) {
            const f32x4& a = fr == 0 ? (fc == 0 ? acc00 : acc01) : (fc == 0 ? acc10 : acc11);
            #pragma unroll
            for (int r = 0; r < 4; ++r) {
                int gi = row_base + fr * 16 + r;
                int gj = col_base + fc * 16;
                float v = a[r];
                if (FLAGS & FLAG_BIAS) v += bias[gj];
                if (FLAGS & FLAG_GELU) v = gelu_f(v);
                if (FLAGS & FLAG_ROWSCALE) v *= rsqrtf((float)(gi & 127) + 1.0f);
                if (FLAGS & FLAG_MASK) { if (gj >= gi) v = 0.f; }
                long ci = (long)bz * cbz + (long)gi * ldc + gj;
                if (OUTB16) Cb[ci] = __float2bfloat16(v);
                else        Cf[ci] = v;
            }
        }
    }
}

// LN over D=512. FINAL=0: LN(x1); FINAL=1: LN(x1 + gf*x2 + gv*x3). OB16 selects out dtype.
template<int FINAL, int OB16>
__global__ __launch_bounds__(256) void ln_kernel(const float* __restrict__ x1,
                                                 const float* __restrict__ x2,
                                                 const float* __restrict__ x3,
                                                 const float* __restrict__ g,
                                                 const float* __restrict__ bb,
                                                 const float* __restrict__ scal,
                                                 void* __restrict__ outv) {
    int row = blockIdx.x, tid = threadIdx.x;
    long base = (long)row * D_;
    int d0 = tid, d1 = tid + 256;
    float v0, v1;
    if (FINAL) {
        float gf = scal[3], gv = scal[4];
        v0 = x1[base + d0] + gf * x2[base + d0] + gv * x3[base + d0];
        v1 = x1[base + d1] + gf * x2[base + d1] + gv * x3[base + d1];
    } else {
        v0 = x1[base + d0];
        v1 = x1[base + d1];
    }
    float s = v0 + v1;
    #pragma unroll
    for (int o = 32; o > 0; o >>= 1) s += __shfl_down(s, o);
    __shared__ float red[8];
    int wid = tid >> 6, lane = tid & 63;
    if (lane == 0) red[wid] = s;
    __syncthreads();
    float mu = (red[0] + red[1] + red[2] + red[3]) * (1.0f / D_);
    float e0 = v0 - mu, e1 = v1 - mu;
    float sq = e0 * e0 + e1 * e1;
    #pragma unroll
    for (int o = 32; o > 0; o >>= 1) sq += __shfl_down(sq, o);
    if (lane == 0) red[4 + wid] = sq;
    __syncthreads();
    float var = (red[4] + red[5] + red[6] + red[7]) * (1.0f / D_);
    float rs = rsqrtf(var + 1e-5f);
    float o0 = e0 * rs * g[d0] + bb[d0];
    float o1 = e1 * rs * g[d1] + bb[d1];
    if (OB16) {
        ((bf16*)outv)[base + d0] = __float2bfloat16(o0);
        ((bf16*)outv)[base + d1] = __float2bfloat16(o1);
    } else {
        ((float*)outv)[base + d0] = o0;
        ((float*)outv)[base + d1] = o1;
    }
}

extern "C" void kernel_launch(void* const* d_in, const int* in_sizes, int n_in,
                              void* d_out, int out_size, void* d_ws, size_t ws_size,
                              hipStream_t stream) {
    const float* e      = (const float*)d_in[0];
    const int*   h      = (const int*)d_in[1];
    const float* sign   = (const float*)d_in[2];
    const float* Wq     = (const float*)d_in[3];
    const float* Wk     = (const float*)d_in[4];
    const float* Wv     = (const float*)d_in[5];
    const float* ro_w1  = (const float*)d_in[6];
    const float* ro_b1  = (const float*)d_in[7];
    const float* ro_w2  = (const float*)d_in[8];
    const float* ro_b2  = (const float*)d_in[9];
    const float* vp_ln_g= (const float*)d_in[10];
    const float* vp_ln_b= (const float*)d_in[11];
    const float* vp_w1  = (const float*)d_in[12];
    const float* vp_b1  = (const float*)d_in[13];
    const float* vp_w2  = (const float*)d_in[14];
    const float* vp_b2  = (const float*)d_in[15];
    const float* ln_g   = (const float*)d_in[16];
    const float* ln_b   = (const float*)d_in[17];
    const float* tq     = (const float*)d_in[18];
    const float* tk     = (const float*)d_in[19];
    const float* om     = (const float*)d_in[20];
    const float* gfr    = (const float*)d_in[21];
    const float* gvr    = (const float*)d_in[22];

    float* ws   = (float*)d_ws;
    float* scal = ws + OFF_SCAL;
    float* qkv  = ws + OFF_QKV;
    float* qc   = ws + OFF_QC;
    float* qs   = ws + OFF_QS;
    float* kc   = ws + OFF_KC;
    float* ks   = ws + OFF_KS;
    float* sk2  = ws + OFF_SK2;
    float* kp   = ws + OFF_KP;
    float* vraw = ws + OFF_VRAW;
    float* vf   = ws + OFF_VF;
    float* hfeat= ws + OFF_HFEAT;
    bf16* eb    = (bf16*)(ws + OFF_EB);
    bf16* wqkvT = (bf16*)(ws + OFF_WQKVT);
    bf16* vp1T  = (bf16*)(ws + OFF_VP1T);
    bf16* vp2T  = (bf16*)(ws + OFF_VP2T);
    bf16* ro1T  = (bf16*)(ws + OFF_RO1T);
    bf16* ro2T  = (bf16*)(ws + OFF_RO2T);
    bf16* qcat  = (bf16*)(ws + OFF_QCAT);
    bf16* kcat  = (bf16*)(ws + OFF_KCAT);
    bf16* dkT   = (bf16*)(ws + OFF_DKT);
    bf16* vTb   = (bf16*)(ws + OFF_VTB);
    bf16* psib  = (bf16*)(ws + OFF_PSIB);
    bf16* scob  = (bf16*)(ws + OFF_SCOB);
    bf16* vlnb  = (bf16*)(ws + OFF_VLNB);
    bf16* v1b   = (bf16*)(ws + OFF_V1B);
    bf16* hidb  = (bf16*)(ws + OFF_HIDB);

    float* ys = (float*)d_out;
    float* kf = ys + (long)BT_ * D_;
    float* hf = kf + (long)B_ * 2 * M_;

    scal_kernel<<<1, 64, 0, stream>>>(tq, tk, om, gfr, gvr, scal);

    // bf16 operand prep
    cast_kernel<<<2048, 256, 0, stream>>>(e, eb, BT_ * D_);
    castT_kernel<<<dim3(16, 16, 1), 256, 0, stream>>>(Wq, wqkvT,            512, 512, 512, 0, 0);
    castT_kernel<<<dim3(16, 16, 1), 256, 0, stream>>>(Wk, wqkvT + 262144,   512, 512, 512, 0, 0);
    castT_kernel<<<dim3(16, 16, 1), 256, 0, stream>>>(Wv, wqkvT + 524288,   512, 512, 512, 0, 0);
    castT_kernel<<<dim3(16, 16, 1), 256, 0, stream>>>(vp_w1, vp1T,          512, 512, 512, 0, 0);
    castT_kernel<<<dim3(16, 16, 1), 256, 0, stream>>>(vp_w2, vp2T,          512, 512, 512, 0, 0);
    castT_kernel<<<dim3(4, 64, 1), 256, 0, stream>>>(ro_w1, ro1T,          2048, 128, 128, 0, 0);
    castT_kernel<<<dim3(16, 4, 1), 256, 0, stream>>>(ro_w2, ro2T,           128, 512, 512, 0, 0);

    // qkv = e @ [Wq|Wk|Wv]  (1024 x 1536 x 512) -> f32
    gemm_mfma<0, 0><<<dim3(24, 16, 1), 256, 0, stream>>>(
        eb, wqkvT, nullptr, qkv, 512, 1536, 0, 0, 0);

    phase_kernel<<<2048, 256, 0, stream>>>(qkv, sign, scal, qc, qs, kc, ks);
    sketch_kernel<<<1024, 256, 0, stream>>>(qc, qs, kc, ks, h, sk2, qcat, kcat);
    prefix_kernel<<<128, 256, 0, stream>>>(sk2, kp, kf);

    // transposed bf16 copies: dkT[c][b][m][t] from sk2; vTb[b][d][t] from qkv v-columns
    castT_kernel<<<dim3(64, 4, 8), 256, 0, stream>>>(sk2,            dkT,           128, 2048, 2048, 262144, 262144);
    castT_kernel<<<dim3(64, 4, 8), 256, 0, stream>>>(sk2 + 2097152L, dkT + 2097152, 128, 2048, 2048, 262144, 262144);
    castT_kernel<<<dim3(16, 4, 8), 256, 0, stream>>>(qkv + 1024,     vTb,           128, 512, 1536, 196608, 65536);

    psi_kernel<<<1024, 256, 0, stream>>>(kp, qc, qs, h, psib);

    // scores[b] = Qcat (128x4096) @ Kcat^T, strict-lower mask, bf16 out
    gemm_mfma<FLAG_MASK, 1><<<dim3(2, 2, 8), 256, 0, stream>>>(
        qcat, kcat, nullptr, scob, 4096, 128, 524288, 524288, 16384);

    // vraw[b] = scores @ v * rsqrt(t+1)  (128x512x128) -> f32
    gemm_mfma<FLAG_ROWSCALE, 0><<<dim3(8, 2, 8), 256, 0, stream>>>(
        scob, vTb, nullptr, vraw, 128, 512, 16384, 65536, 65536);

    ln_kernel<0, 1><<<1024, 256, 0, stream>>>(vraw, nullptr, nullptr, vp_ln_g, vp_ln_b, scal, vlnb);

    // vp MLP
    gemm_mfma<FLAG_BIAS | FLAG_GELU, 1><<<dim3(8, 16, 1), 256, 0, stream>>>(
        vlnb, vp1T, vp_b1, v1b, 512, 512, 0, 0, 0);
    gemm_mfma<FLAG_BIAS, 0><<<dim3(8, 16, 1), 256, 0, stream>>>(
        v1b, vp2T, vp_b2, vf, 512, 512, 0, 0, 0);

    // hid = gelu(psi @ ro_w1 + b1) (1024x128x2048) -> bf16
    gemm_mfma<FLAG_BIAS | FLAG_GELU, 1><<<dim3(2, 16, 1), 256, 0, stream>>>(
        psib, ro1T, ro_b1, hidb, 2048, 128, 0, 0, 0);
    // hfeat = hid @ ro_w2 + b2 (1024x512x128) -> f32
    gemm_mfma<FLAG_BIAS, 0><<<dim3(8, 16, 1), 256, 0, stream>>>(
        hidb, ro2T, ro_b2, hfeat, 128, 512, 0, 0, 0);

    // ys = LN(e + gf*hfeat + gv*vf)
    ln_kernel<1, 0><<<1024, 256, 0, stream>>>(e, hfeat, vf, ln_g, ln_b, scal, ys);

    // Hf[b,c] = vT (512x128) @ dK_c^T (2048x128)^T -> f32 (512x2048)
    gemm_mfma<0, 0><<<dim3(32, 8, 8), 256, 0, stream>>>(
        vTb, dkT, nullptr, hf, 128, 2048, 65536, 262144, 2097152);
    gemm_mfma<0, 0><<<dim3(32, 8, 8), 256, 0, stream>>>(
        vTb, dkT + 2097152, nullptr, hf + 1048576, 128, 2048, 65536, 262144, 2097152);
}

// Round 3
// 250.202 us; speedup vs baseline: 2.8345x; 1.4758x over previous
//
#include <hip/hip_runtime.h>
#include <hip/hip_bf16.h>
#include <math.h>

#define B_   8
#define T_   128
#define D_   512
#define M_   2048
#define HID_ 128
#define BT_  1024
#define FFT_N 2048

typedef __attribute__((ext_vector_type(8))) short short8t;
typedef __attribute__((ext_vector_type(4))) float f32x4;
typedef __hip_bfloat16 bf16;

// ws layout (float offsets; all multiples of 16 -> 64B aligned)
#define OFF_SCAL   0L
#define OFF_QKV    16L                            // 1024*1536 f32
#define OFF_SK2    (OFF_QKV + 1572864L)           // [dKre|dKim] f32, 2*BT*M
#define OFF_KP     (OFF_SK2 + 4194304L)           // [KR|KI] f32 exclusive prefix
#define OFF_VRAW   (OFF_KP + 4194304L)
#define OFF_VF     (OFF_VRAW + 524288L)
#define OFF_HFEAT  (OFF_VF + 524288L)
// bf16 buffers (size in floats = elems/2)
#define OFF_EB     (OFF_HFEAT + 524288L)          // 1024x512
#define OFF_WQKVT  (OFF_EB + 262144L)             // 1536x512
#define OFF_VP1T   (OFF_WQKVT + 393216L)          // 512x512
#define OFF_VP2T   (OFF_VP1T + 131072L)
#define OFF_RO1T   (OFF_VP2T + 131072L)           // 128x2048
#define OFF_RO2T   (OFF_RO1T + 131072L)           // 512x128
#define OFF_QCAT   (OFF_RO2T + 32768L)            // 1024x4096
#define OFF_KCAT   (OFF_QCAT + 2097152L)          // 1024x4096
#define OFF_DKT    (OFF_KCAT + 2097152L)          // 2x8x2048x128
#define OFF_VTB    (OFF_DKT + 2097152L)           // 8x512x128
#define OFF_PSIB   (OFF_VTB + 262144L)            // 1024x2048
#define OFF_SCOB   (OFF_PSIB + 1048576L)          // 8x128x128
#define OFF_VLNB   (OFF_SCOB + 65536L)            // 1024x512
#define OFF_V1B    (OFF_VLNB + 262144L)           // 1024x512
#define OFF_HIDB   (OFF_V1B + 262144L)            // 1024x128

#define FLAG_BIAS     1
#define FLAG_GELU     2
#define FLAG_ROWSCALE 4
#define FLAG_MASK     16

__device__ __forceinline__ float gelu_f(float x) {
    return 0.5f * x * (1.0f + erff(x * 0.70710678118654752440f));
}

__global__ void scal_kernel(const float* tq, const float* tk, const float* om,
                            const float* gf, const float* gv, float* scal) {
    if (threadIdx.x == 0) {
        scal[0] = 0.5f * tanhf(tq[0]);
        scal[1] = 0.5f * tanhf(tk[0]);
        scal[2] = 0.5f * tanhf(om[0]);
        scal[3] = 0.25f / (1.0f + expf(-gf[0]));
        scal[4] = 0.25f / (1.0f + expf(-gv[0]));
    }
}

__global__ __launch_bounds__(256) void cast_kernel(const float* __restrict__ in,
                                                   bf16* __restrict__ out, int n) {
    int i = blockIdx.x * 256 + threadIdx.x;
    if (i < n) out[i] = __float2bfloat16(in[i]);
}

// tiled transpose-cast: in f32 [R][C] (ld_in, batch bs_in) -> out bf16 [C][R] (batch bs_out)
__global__ __launch_bounds__(256) void castT_kernel(const float* __restrict__ in,
                                                    bf16* __restrict__ out,
                                                    int R, int C, int ld_in,
                                                    long bs_in, long bs_out) {
    __shared__ float tile[32][33];
    int b = blockIdx.z;
    int c0 = blockIdx.x * 32, r0 = blockIdx.y * 32;
    int tx = threadIdx.x & 31, ty = threadIdx.x >> 5;
    for (int rr = ty; rr < 32; rr += 8) {
        int r = r0 + rr, c = c0 + tx;
        tile[rr][tx] = (r < R && c < C) ? in[(long)b * bs_in + (long)r * ld_in + c] : 0.f;
    }
    __syncthreads();
    for (int cc = ty; cc < 32; cc += 8) {
        int c = c0 + cc, r = r0 + tx;
        if (c < C && r < R) out[(long)b * bs_out + (long)c * R + r] = __float2bfloat16(tile[tx][cc]);
    }
}

// batched 512x512 transpose-cast for 5 weights in one launch
__global__ __launch_bounds__(256) void castT5_kernel(const float* w0, const float* w1,
                                                     const float* w2, const float* w3,
                                                     const float* w4,
                                                     bf16* d0, bf16* d1, bf16* d2,
                                                     bf16* d3, bf16* d4) {
    __shared__ float tile[32][33];
    int z = blockIdx.z;
    const float* src; bf16* dst;
    if (z == 0)      { src = w0; dst = d0; }
    else if (z == 1) { src = w1; dst = d1; }
    else if (z == 2) { src = w2; dst = d2; }
    else if (z == 3) { src = w3; dst = d3; }
    else             { src = w4; dst = d4; }
    int c0 = blockIdx.x * 32, r0 = blockIdx.y * 32;
    int tx = threadIdx.x & 31, ty = threadIdx.x >> 5;
    for (int rr = ty; rr < 32; rr += 8)
        tile[rr][tx] = src[(long)(r0 + rr) * 512 + c0 + tx];
    __syncthreads();
    for (int cc = ty; cc < 32; cc += 8)
        dst[(long)(c0 + cc) * 512 + r0 + tx] = __float2bfloat16(tile[tx][cc]);
}

// sketch (phase fused): SK2 f32 = [dKre|dKim]; qcat bf16 = [Qre|Qim]; kcat bf16 = [dKre|-dKim]
__global__ __launch_bounds__(256) void sketch_kernel(const float* __restrict__ qkv,
                                                     const float* __restrict__ sign,
                                                     const float* __restrict__ scal,
                                                     const int* __restrict__ h,
                                                     float* __restrict__ SK2,
                                                     bf16* __restrict__ qcat,
                                                     bf16* __restrict__ kcat) {
    int bt = blockIdx.x;
    int tid = threadIdx.x;
    __shared__ float s0[M_], s1[M_], s2[M_], s3[M_];
    for (int j = tid; j < M_; j += 256) { s0[j] = 0.f; s1[j] = 0.f; s2[j] = 0.f; s3[j] = 0.f; }
    __syncthreads();
    int t = bt & 127;
    float thq = scal[0], thk = scal[1], omg = scal[2];
    float ft = (float)t;
    for (int i = tid; i < D_; i += 256) {
        float q = qkv[(long)bt * 1536 + i];
        float k = qkv[(long)bt * 1536 + 512 + i];
        float sg = sign[i];
        float sq_, cq_, sk_, ck_;
        sincosf(thq * q - omg * ft, &sq_, &cq_);
        sincosf(thk * k + omg * ft, &sk_, &ck_);
        int m = h[i];
        atomicAdd(&s0[m], q * cq_ * sg);
        atomicAdd(&s1[m], q * sq_ * sg);
        atomicAdd(&s2[m], k * ck_ * sg);
        atomicAdd(&s3[m], k * sk_ * sg);
    }
    __syncthreads();
    long ob = (long)bt * M_;
    long qb = (long)bt * 4096;
    for (int j = tid; j < M_; j += 256) {
        SK2[ob + j]                  = s2[j];
        SK2[(long)BT_ * M_ + ob + j] = s3[j];
        qcat[qb + j]        = __float2bfloat16(s0[j]);
        qcat[qb + 2048 + j] = __float2bfloat16(s1[j]);
        kcat[qb + j]        = __float2bfloat16(s2[j]);
        kcat[qb + 2048 + j] = __float2bfloat16(-s3[j]);
    }
}

// exclusive prefix over t of SK2 -> KP; totals -> kf_out
__global__ __launch_bounds__(256) void prefix_kernel(const float* __restrict__ SK2,
                                                     float* __restrict__ KP,
                                                     float* __restrict__ kf_out) {
    int idx = blockIdx.x * 256 + threadIdx.x;
    if (idx >= 2 * B_ * M_) return;
    int m = idx & (M_ - 1);
    int bm = idx >> 11;
    int b = bm & 7;
    int comp = bm >> 3;
    const float* src = SK2 + (long)comp * BT_ * M_ + (long)b * T_ * M_ + m;
    float* dst = KP + (long)comp * BT_ * M_ + (long)b * T_ * M_ + m;
    float acc = 0.f;
    for (int t = 0; t < T_; ++t) {
        dst[(long)t * M_] = acc;
        acc += src[(long)t * M_];
    }
    kf_out[((long)b * 2 + comp) * M_ + m] = acc;
}

// ---- 2048-pt Stockham radix-2 FFT in LDS ----
// tw[p] = exp(-i*pi*p/1024), p in [0,1024)
// dir=+1: forward (e^-); dir=-1: inverse unnormalized (e^+)
template<int DIR>
__device__ __forceinline__ int fft_run(float2 (*fb)[FFT_N], const float2* tw,
                                       int s, int d, int tid) {
    int m = 1;
    #pragma unroll 1
    for (int stage = 0; stage < 11; ++stage) {
        #pragma unroll
        for (int u = 0; u < 4; ++u) {
            int q = u * 256 + tid;
            int k = q & (m - 1);
            int p = q - k;                       // j*m (twiddle index)
            float2 c0 = fb[s][q];
            float2 c1 = fb[s][q + 1024];
            float2 w = tw[p];
            float wy = (DIR > 0) ? w.y : -w.y;
            float ex = c0.x + c1.x, ey = c0.y + c1.y;
            float ox = c0.x - c1.x, oy = c0.y - c1.y;
            float rx = ox * w.x - oy * wy;
            float ry = ox * wy + oy * w.x;
            int wi = 2 * p + k;
            fb[d][wi]     = make_float2(ex, ey);
            fb[d][wi + m] = make_float2(rx, ry);
        }
        m <<= 1;
        int tmp = s; s = d; d = tmp;
        __syncthreads();
    }
    return s;   // result buffer index
}

// psi[b,t,:] = Re(IDFT(DFT(Q_sketch) * DFT(K_prefix))) / (N^1.5 * sqrt(t+1)) -> bf16
__global__ __launch_bounds__(256) void psi_fft_kernel(const float* __restrict__ qkv,
                                                      const float* __restrict__ sign,
                                                      const float* __restrict__ scal,
                                                      const int* __restrict__ h,
                                                      const float* __restrict__ KP,
                                                      bf16* __restrict__ psi_b) {
    __shared__ float2 fb[3][FFT_N];     // 48 KB ping/pong/hold
    __shared__ float2 tw[FFT_N / 2];    // 8 KB twiddles
    int bt = blockIdx.x;
    int tid = threadIdx.x;
    int t = bt & 127;

    for (int p = tid; p < 1024; p += 256) {
        float a = (float)p * (3.14159265358979323846f / 1024.0f);
        float sv, cv;
        sincosf(a, &sv, &cv);
        tw[p] = make_float2(cv, -sv);
    }
    for (int j = tid; j < FFT_N; j += 256) {
        fb[1][j] = make_float2(0.f, 0.f);   // Q accumulator
        fb[0][j] = make_float2(KP[(long)bt * M_ + j],
                               KP[(long)BT_ * M_ + (long)bt * M_ + j]);
    }
    __syncthreads();
    {   // scatter sparse Q sketch into fb[1]
        float thq = scal[0], omg = scal[2];
        float ft = (float)t;
        for (int i = tid; i < D_; i += 256) {
            float q = qkv[(long)bt * 1536 + i];
            float sg = sign[i];
            float sv, cv;
            sincosf(thq * q - omg * ft, &sv, &cv);
            int m = h[i];
            atomicAdd(&fb[1][m].x, q * cv * sg);
            atomicAdd(&fb[1][m].y, q * sv * sg);
        }
    }
    __syncthreads();
    int rk = fft_run<1>(fb, tw, 0, 2, tid);     // FFT(K): ends in fb[2]
    int rq = fft_run<1>(fb, tw, 1, 0, tid);     // FFT(Q): ends in fb[0]
    // cmul -> fb[1]
    for (int u = 0; u < 8; ++u) {
        int j = u * 256 + tid;
        float2 a = fb[rq][j];
        float2 b = fb[rk][j];
        fb[1][j] = make_float2(a.x * b.x - a.y * b.y, a.x * b.y + a.y * b.x);
    }
    __syncthreads();
    int ri = fft_run<-1>(fb, tw, 1, 0, tid);    // IDFT (unnormalized): ends in fb[0]
    float scale = rsqrtf((float)(t + 1)) * (1.0f / 92681.900089f);  // 1/2048^1.5
    for (int u = 0; u < 8; ++u) {
        int j = u * 256 + tid;
        psi_b[(long)bt * M_ + j] = __float2bfloat16(fb[ri][j].x * scale);
    }
}

// MFMA bf16 TN GEMM: C[M,N] = A[M,K] * Bt[N,K]^T. 64x64 tile, 4 waves.
template<int FLAGS, int OUTB16>
__global__ __launch_bounds__(256) void gemm_mfma(
    const bf16* __restrict__ A, const bf16* __restrict__ Bt,
    const float* __restrict__ bias, void* __restrict__ Cv,
    int K, int ldc, long abz, long bbz, long cbz)
{
    __shared__ __align__(16) bf16 As[64][40];
    __shared__ __align__(16) bf16 Bs[64][40];
    int bz = blockIdx.z;
    const bf16* Ab = A + (long)bz * abz + (long)blockIdx.y * 64 * K;
    const bf16* Bb = Bt + (long)bz * bbz + (long)blockIdx.x * 64 * K;
    int tid = threadIdx.x;
    int lrow = tid >> 2;
    int lk = (tid & 3) * 8;
    int w = tid >> 6, lane = tid & 63;
    int wr = (w >> 1) * 32, wc = (w & 1) * 32;
    int fm = lane & 15, fk = (lane >> 4) * 8;
    f32x4 acc00 = {0.f,0.f,0.f,0.f}, acc01 = acc00, acc10 = acc00, acc11 = acc00;

    for (int kt = 0; kt < K; kt += 32) {
        *(float4*)&As[lrow][lk] = *(const float4*)&Ab[(long)lrow * K + kt + lk];
        *(float4*)&Bs[lrow][lk] = *(const float4*)&Bb[(long)lrow * K + kt + lk];
        __syncthreads();
        short8t a0 = *(const short8t*)&As[wr + fm][fk];
        short8t a1 = *(const short8t*)&As[wr + 16 + fm][fk];
        short8t b0 = *(const short8t*)&Bs[wc + fm][fk];
        short8t b1 = *(const short8t*)&Bs[wc + 16 + fm][fk];
        acc00 = __builtin_amdgcn_mfma_f32_16x16x32_bf16(a0, b0, acc00, 0, 0, 0);
        acc01 = __builtin_amdgcn_mfma_f32_16x16x32_bf16(a0, b1, acc01, 0, 0, 0);
        acc10 = __builtin_amdgcn_mfma_f32_16x16x32_bf16(a1, b0, acc10, 0, 0, 0);
        acc11 = __builtin_amdgcn_mfma_f32_16x16x32_bf16(a1, b1, acc11, 0, 0, 0);
        __syncthreads();
    }

    float* Cf = (float*)Cv;
    bf16* Cb = (bf16*)Cv;
    int row_base = blockIdx.y * 64 + wr + (lane >> 4) * 4;
    int col_base = blockIdx.x * 64 + wc + fm;
    #pragma unroll
    for (int fr = 0; fr < 2; ++fr) {
        #pragma unroll
        for (int fc = 0; fc < 2; ++fc) {
            const f32x4& a = fr == 0 ? (fc == 0 ? acc00 : acc01) : (fc == 0 ? acc10 : acc11);
            #pragma unroll
            for (int r = 0; r < 4; ++r) {
                int gi = row_base + fr * 16 + r;
                int gj = col_base + fc * 16;
                float v = a[r];
                if (FLAGS & FLAG_BIAS) v += bias[gj];
                if (FLAGS & FLAG_GELU) v = gelu_f(v);
                if (FLAGS & FLAG_ROWSCALE) v *= rsqrtf((float)(gi & 127) + 1.0f);
                if (FLAGS & FLAG_MASK) { if (gj >= gi) v = 0.f; }
                long ci = (long)bz * cbz + (long)gi * ldc + gj;
                if (OUTB16) Cb[ci] = __float2bfloat16(v);
                else        Cf[ci] = v;
            }
        }
    }
}

// LN over D=512. FINAL=0: LN(x1); FINAL=1: LN(x1 + gf*x2 + gv*x3). OB16 selects out dtype.
template<int FINAL, int OB16>
__global__ __launch_bounds__(256) void ln_kernel(const float* __restrict__ x1,
                                                 const float* __restrict__ x2,
                                                 const float* __restrict__ x3,
                                                 const float* __restrict__ g,
                                                 const float* __restrict__ bb,
                                                 const float* __restrict__ scal,
                                                 void* __restrict__ outv) {
    int row = blockIdx.x, tid = threadIdx.x;
    long base = (long)row * D_;
    int d0 = tid, d1 = tid + 256;
    float v0, v1;
    if (FINAL) {
        float gf = scal[3], gv = scal[4];
        v0 = x1[base + d0] + gf * x2[base + d0] + gv * x3[base + d0];
        v1 = x1[base + d1] + gf * x2[base + d1] + gv * x3[base + d1];
    } else {
        v0 = x1[base + d0];
        v1 = x1[base + d1];
    }
    float s = v0 + v1;
    #pragma unroll
    for (int o = 32; o > 0; o >>= 1) s += __shfl_down(s, o);
    __shared__ float red[8];
    int wid = tid >> 6, lane = tid & 63;
    if (lane == 0) red[wid] = s;
    __syncthreads();
    float mu = (red[0] + red[1] + red[2] + red[3]) * (1.0f / D_);
    float e0 = v0 - mu, e1 = v1 - mu;
    float sq = e0 * e0 + e1 * e1;
    #pragma unroll
    for (int o = 32; o > 0; o >>= 1) sq += __shfl_down(sq, o);
    if (lane == 0) red[4 + wid] = sq;
    __syncthreads();
    float var = (red[4] + red[5] + red[6] + red[7]) * (1.0f / D_);
    float rs = rsqrtf(var + 1e-5f);
    float o0 = e0 * rs * g[d0] + bb[d0];
    float o1 = e1 * rs * g[d1] + bb[d1];
    if (OB16) {
        ((bf16*)outv)[base + d0] = __float2bfloat16(o0);
        ((bf16*)outv)[base + d1] = __float2bfloat16(o1);
    } else {
        ((float*)outv)[base + d0] = o0;
        ((float*)outv)[base + d1] = o1;
    }
}

extern "C" void kernel_launch(void* const* d_in, const int* in_sizes, int n_in,
                              void* d_out, int out_size, void* d_ws, size_t ws_size,
                              hipStream_t stream) {
    const float* e      = (const float*)d_in[0];
    const int*   h      = (const int*)d_in[1];
    const float* sign   = (const float*)d_in[2];
    const float* Wq     = (const float*)d_in[3];
    const float* Wk     = (const float*)d_in[4];
    const float* Wv     = (const float*)d_in[5];
    const float* ro_w1  = (const float*)d_in[6];
    const float* ro_b1  = (const float*)d_in[7];
    const float* ro_w2  = (const float*)d_in[8];
    const float* ro_b2  = (const float*)d_in[9];
    const float* vp_ln_g= (const float*)d_in[10];
    const float* vp_ln_b= (const float*)d_in[11];
    const float* vp_w1  = (const float*)d_in[12];
    const float* vp_b1  = (const float*)d_in[13];
    const float* vp_w2  = (const float*)d_in[14];
    const float* vp_b2  = (const float*)d_in[15];
    const float* ln_g   = (const float*)d_in[16];
    const float* ln_b   = (const float*)d_in[17];
    const float* tq     = (const float*)d_in[18];
    const float* tk     = (const float*)d_in[19];
    const float* om     = (const float*)d_in[20];
    const float* gfr    = (const float*)d_in[21];
    const float* gvr    = (const float*)d_in[22];

    float* ws   = (float*)d_ws;
    float* scal = ws + OFF_SCAL;
    float* qkv  = ws + OFF_QKV;
    float* sk2  = ws + OFF_SK2;
    float* kp   = ws + OFF_KP;
    float* vraw = ws + OFF_VRAW;
    float* vf   = ws + OFF_VF;
    float* hfeat= ws + OFF_HFEAT;
    bf16* eb    = (bf16*)(ws + OFF_EB);
    bf16* wqkvT = (bf16*)(ws + OFF_WQKVT);
    bf16* vp1T  = (bf16*)(ws + OFF_VP1T);
    bf16* vp2T  = (bf16*)(ws + OFF_VP2T);
    bf16* ro1T  = (bf16*)(ws + OFF_RO1T);
    bf16* ro2T  = (bf16*)(ws + OFF_RO2T);
    bf16* qcat  = (bf16*)(ws + OFF_QCAT);
    bf16* kcat  = (bf16*)(ws + OFF_KCAT);
    bf16* dkT   = (bf16*)(ws + OFF_DKT);
    bf16* vTb   = (bf16*)(ws + OFF_VTB);
    bf16* psib  = (bf16*)(ws + OFF_PSIB);
    bf16* scob  = (bf16*)(ws + OFF_SCOB);
    bf16* vlnb  = (bf16*)(ws + OFF_VLNB);
    bf16* v1b   = (bf16*)(ws + OFF_V1B);
    bf16* hidb  = (bf16*)(ws + OFF_HIDB);

    float* ys = (float*)d_out;
    float* kf = ys + (long)BT_ * D_;
    float* hf = kf + (long)B_ * 2 * M_;

    scal_kernel<<<1, 64, 0, stream>>>(tq, tk, om, gfr, gvr, scal);

    // bf16 operand prep
    cast_kernel<<<2048, 256, 0, stream>>>(e, eb, BT_ * D_);
    castT5_kernel<<<dim3(16, 16, 5), 256, 0, stream>>>(
        Wq, Wk, Wv, vp_w1, vp_w2,
        wqkvT, wqkvT + 262144, wqkvT + 524288, vp1T, vp2T);
    castT_kernel<<<dim3(4, 64, 1), 256, 0, stream>>>(ro_w1, ro1T, 2048, 128, 128, 0, 0);
    castT_kernel<<<dim3(16, 4, 1), 256, 0, stream>>>(ro_w2, ro2T,  128, 512, 512, 0, 0);

    // qkv = e @ [Wq|Wk|Wv]  (1024 x 1536 x 512) -> f32
    gemm_mfma<0, 0><<<dim3(24, 16, 1), 256, 0, stream>>>(
        eb, wqkvT, nullptr, qkv, 512, 1536, 0, 0, 0);

    sketch_kernel<<<1024, 256, 0, stream>>>(qkv, sign, scal, h, sk2, qcat, kcat);
    prefix_kernel<<<128, 256, 0, stream>>>(sk2, kp, kf);

    // psi via 3x 2048-pt FFT per (b,t)
    psi_fft_kernel<<<1024, 256, 0, stream>>>(qkv, sign, scal, h, kp, psib);

    // transposed bf16 copies: dkT[c][b][m][t] from sk2; vTb[b][d][t] from qkv v-columns
    castT_kernel<<<dim3(64, 4, 8), 256, 0, stream>>>(sk2,            dkT,           128, 2048, 2048, 262144, 262144);
    castT_kernel<<<dim3(64, 4, 8), 256, 0, stream>>>(sk2 + 2097152L, dkT + 2097152, 128, 2048, 2048, 262144, 262144);
    castT_kernel<<<dim3(16, 4, 8), 256, 0, stream>>>(qkv + 1024,     vTb,           128, 512, 1536, 196608, 65536);

    // scores[b] = Qcat (128x4096) @ Kcat^T, strict-lower mask, bf16 out
    gemm_mfma<FLAG_MASK, 1><<<dim3(2, 2, 8), 256, 0, stream>>>(
        qcat, kcat, nullptr, scob, 4096, 128, 524288, 524288, 16384);

    // vraw[b] = scores @ v * rsqrt(t+1)  (128x512x128) -> f32
    gemm_mfma<FLAG_ROWSCALE, 0><<<dim3(8, 2, 8), 256, 0, stream>>>(
        scob, vTb, nullptr, vraw, 128, 512, 16384, 65536, 65536);

    ln_kernel<0, 1><<<1024, 256, 0, stream>>>(vraw, nullptr, nullptr, vp_ln_g, vp_ln_b, scal, vlnb);

    // vp MLP
    gemm_mfma<FLAG_BIAS | FLAG_GELU, 1><<<dim3(8, 16, 1), 256, 0, stream>>>(
        vlnb, vp1T, vp_b1, v1b, 512, 512, 0, 0, 0);
    gemm_mfma<FLAG_BIAS, 0><<<dim3(8, 16, 1), 256, 0, stream>>>(
        v1b, vp2T, vp_b2, vf, 512, 512, 0, 0, 0);

    // hid = gelu(psi @ ro_w1 + b1) (1024x128x2048) -> bf16
    gemm_mfma<FLAG_BIAS | FLAG_GELU, 1><<<dim3(2, 16, 1), 256, 0, stream>>>(
        psib, ro1T, ro_b1, hidb, 2048, 128, 0, 0, 0);
    // hfeat = hid @ ro_w2 + b2 (1024x512x128) -> f32
    gemm_mfma<FLAG_BIAS, 0><<<dim3(8, 16, 1), 256, 0, stream>>>(
        hidb, ro2T, ro_b2, hfeat, 128, 512, 0, 0, 0);

    // ys = LN(e + gf*hfeat + gv*vf)
    ln_kernel<1, 0><<<1024, 256, 0, stream>>>(e, hfeat, vf, ln_g, ln_b, scal, ys);

    // Hf[b,c] = vT (512x128) @ dK_c^T (2048x128)^T -> f32 (512x2048)
    gemm_mfma<0, 0><<<dim3(32, 8, 8), 256, 0, stream>>>(
        vTb, dkT, nullptr, hf, 128, 2048, 65536, 262144, 2097152);
    gemm_mfma<0, 0><<<dim3(32, 8, 8), 256, 0, stream>>>(
        vTb, dkT + 2097152, nullptr, hf + 1048576, 128, 2048, 65536, 262144, 2097152);
}

// Round 4
// 215.094 us; speedup vs baseline: 3.2971x; 1.1632x over previous
//
#include <hip/hip_runtime.h>
#include <hip/hip_bf16.h>
#include <math.h>

#define B_   8
#define T_   128
#define D_   512
#define M_   2048
#define HID_ 128
#define BT_  1024
#define FFT_N 2048

typedef __attribute__((ext_vector_type(8))) short short8t;
typedef __attribute__((ext_vector_type(4))) float f32x4;
typedef __hip_bfloat16 bf16;

// ws layout (float offsets; all multiples of 16 -> 64B aligned)
#define OFF_SCAL   0L
#define OFF_QKV    16L                            // 1024*1536 f32
#define OFF_SK2    (OFF_QKV + 1572864L)           // [dKre|dKim] f32, 2*BT*M
#define OFF_KP     (OFF_SK2 + 4194304L)           // [KR|KI] f32 exclusive prefix
#define OFF_VRAW   (OFF_KP + 4194304L)
#define OFF_VF     (OFF_VRAW + 524288L)
#define OFF_HFEAT  (OFF_VF + 524288L)
// bf16 buffers (size in floats = elems/2)
#define OFF_EB     (OFF_HFEAT + 524288L)          // 1024x512
#define OFF_WQKVT  (OFF_EB + 262144L)             // 1536x512
#define OFF_VP1T   (OFF_WQKVT + 393216L)          // 512x512
#define OFF_VP2T   (OFF_VP1T + 131072L)
#define OFF_RO1T   (OFF_VP2T + 131072L)           // 128x2048
#define OFF_RO2T   (OFF_RO1T + 131072L)           // 512x128
#define OFF_QCAT   (OFF_RO2T + 32768L)            // 1024x4096
#define OFF_KCAT   (OFF_QCAT + 2097152L)          // 1024x4096
#define OFF_DKT    (OFF_KCAT + 2097152L)          // 2x8x2048x128
#define OFF_VTB    (OFF_DKT + 2097152L)           // 8x512x128
#define OFF_PSIB   (OFF_VTB + 262144L)            // 1024x2048
#define OFF_SCOB   (OFF_PSIB + 1048576L)          // 8x128x128 bf16
#define OFF_VLNB   (OFF_SCOB + 65536L)            // 1024x512
#define OFF_V1B    (OFF_VLNB + 262144L)           // 1024x512
#define OFF_HIDB   (OFF_V1B + 262144L)            // 1024x128
#define OFF_SCOA   (OFF_HIDB + 65536L)            // 8x128x128 f32 split-K accumulator

#define FLAG_BIAS     1
#define FLAG_GELU     2
#define FLAG_ROWSCALE 4
#define FLAG_ATOMIC   8
#define FLAG_MASK     16
#define FLAG_HFB      32

__device__ __forceinline__ float gelu_f(float x) {
    return 0.5f * x * (1.0f + erff(x * 0.70710678118654752440f));
}

__global__ void scal_kernel(const float* tq, const float* tk, const float* om,
                            const float* gf, const float* gv, float* scal) {
    if (threadIdx.x == 0) {
        scal[0] = 0.5f * tanhf(tq[0]);
        scal[1] = 0.5f * tanhf(tk[0]);
        scal[2] = 0.5f * tanhf(om[0]);
        scal[3] = 0.25f / (1.0f + expf(-gf[0]));
        scal[4] = 0.25f / (1.0f + expf(-gv[0]));
    }
}

__global__ __launch_bounds__(256) void cast_kernel(const float* __restrict__ in,
                                                   bf16* __restrict__ out, int n) {
    int i = blockIdx.x * 256 + threadIdx.x;
    if (i < n) out[i] = __float2bfloat16(in[i]);
}

// tiled transpose-cast: in f32 [R][C] (ld_in, batch bs_in) -> out bf16 [C][R] (batch bs_out)
__global__ __launch_bounds__(256) void castT_kernel(const float* __restrict__ in,
                                                    bf16* __restrict__ out,
                                                    int R, int C, int ld_in,
                                                    long bs_in, long bs_out) {
    __shared__ float tile[32][33];
    int b = blockIdx.z;
    int c0 = blockIdx.x * 32, r0 = blockIdx.y * 32;
    int tx = threadIdx.x & 31, ty = threadIdx.x >> 5;
    for (int rr = ty; rr < 32; rr += 8) {
        int r = r0 + rr, c = c0 + tx;
        tile[rr][tx] = (r < R && c < C) ? in[(long)b * bs_in + (long)r * ld_in + c] : 0.f;
    }
    __syncthreads();
    for (int cc = ty; cc < 32; cc += 8) {
        int c = c0 + cc, r = r0 + tx;
        if (c < C && r < R) out[(long)b * bs_out + (long)c * R + r] = __float2bfloat16(tile[tx][cc]);
    }
}

// batched 512x512 transpose-cast for 5 weights in one launch
__global__ __launch_bounds__(256) void castT5_kernel(const float* w0, const float* w1,
                                                     const float* w2, const float* w3,
                                                     const float* w4,
                                                     bf16* d0, bf16* d1, bf16* d2,
                                                     bf16* d3, bf16* d4) {
    __shared__ float tile[32][33];
    int z = blockIdx.z;
    const float* src; bf16* dst;
    if (z == 0)      { src = w0; dst = d0; }
    else if (z == 1) { src = w1; dst = d1; }
    else if (z == 2) { src = w2; dst = d2; }
    else if (z == 3) { src = w3; dst = d3; }
    else             { src = w4; dst = d4; }
    int c0 = blockIdx.x * 32, r0 = blockIdx.y * 32;
    int tx = threadIdx.x & 31, ty = threadIdx.x >> 5;
    for (int rr = ty; rr < 32; rr += 8)
        tile[rr][tx] = src[(long)(r0 + rr) * 512 + c0 + tx];
    __syncthreads();
    for (int cc = ty; cc < 32; cc += 8)
        dst[(long)(c0 + cc) * 512 + r0 + tx] = __float2bfloat16(tile[tx][cc]);
}

// sketch (phase fused): SK2 f32 = [dKre|dKim]; qcat bf16 = [Qre|Qim]; kcat bf16 = [dKre|-dKim]
__global__ __launch_bounds__(256) void sketch_kernel(const float* __restrict__ qkv,
                                                     const float* __restrict__ sign,
                                                     const float* __restrict__ scal,
                                                     const int* __restrict__ h,
                                                     float* __restrict__ SK2,
                                                     bf16* __restrict__ qcat,
                                                     bf16* __restrict__ kcat) {
    int bt = blockIdx.x;
    int tid = threadIdx.x;
    __shared__ float s0[M_], s1[M_], s2[M_], s3[M_];
    for (int j = tid; j < M_; j += 256) { s0[j] = 0.f; s1[j] = 0.f; s2[j] = 0.f; s3[j] = 0.f; }
    __syncthreads();
    int t = bt & 127;
    float thq = scal[0], thk = scal[1], omg = scal[2];
    float ft = (float)t;
    for (int i = tid; i < D_; i += 256) {
        float q = qkv[(long)bt * 1536 + i];
        float k = qkv[(long)bt * 1536 + 512 + i];
        float sg = sign[i];
        float sq_, cq_, sk_, ck_;
        sincosf(thq * q - omg * ft, &sq_, &cq_);
        sincosf(thk * k + omg * ft, &sk_, &ck_);
        int m = h[i];
        atomicAdd(&s0[m], q * cq_ * sg);
        atomicAdd(&s1[m], q * sq_ * sg);
        atomicAdd(&s2[m], k * ck_ * sg);
        atomicAdd(&s3[m], k * sk_ * sg);
    }
    __syncthreads();
    long ob = (long)bt * M_;
    long qb = (long)bt * 4096;
    for (int j = tid; j < M_; j += 256) {
        SK2[ob + j]                  = s2[j];
        SK2[(long)BT_ * M_ + ob + j] = s3[j];
        qcat[qb + j]        = __float2bfloat16(s0[j]);
        qcat[qb + 2048 + j] = __float2bfloat16(s1[j]);
        kcat[qb + j]        = __float2bfloat16(s2[j]);
        kcat[qb + 2048 + j] = __float2bfloat16(-s3[j]);
    }
}

// exclusive prefix over t of SK2 -> KP; totals -> kf_out
__global__ __launch_bounds__(256) void prefix_kernel(const float* __restrict__ SK2,
                                                     float* __restrict__ KP,
                                                     float* __restrict__ kf_out) {
    int idx = blockIdx.x * 256 + threadIdx.x;
    if (idx >= 2 * B_ * M_) return;
    int m = idx & (M_ - 1);
    int bm = idx >> 11;
    int b = bm & 7;
    int comp = bm >> 3;
    const float* src = SK2 + (long)comp * BT_ * M_ + (long)b * T_ * M_ + m;
    float* dst = KP + (long)comp * BT_ * M_ + (long)b * T_ * M_ + m;
    float acc = 0.f;
    #pragma unroll 4
    for (int t = 0; t < T_; ++t) {
        dst[(long)t * M_] = acc;
        acc += src[(long)t * M_];
    }
    kf_out[((long)b * 2 + comp) * M_ + m] = acc;
}

// ---- 2048-pt Stockham radix-2 FFT in LDS ----
template<int DIR>
__device__ __forceinline__ int fft_run(float2 (*fb)[FFT_N], const float2* tw,
                                       int s, int d, int tid) {
    int m = 1;
    #pragma unroll 1
    for (int stage = 0; stage < 11; ++stage) {
        #pragma unroll
        for (int u = 0; u < 4; ++u) {
            int q = u * 256 + tid;
            int k = q & (m - 1);
            int p = q - k;
            float2 c0 = fb[s][q];
            float2 c1 = fb[s][q + 1024];
            float2 w = tw[p];
            float wy = (DIR > 0) ? w.y : -w.y;
            float ex = c0.x + c1.x, ey = c0.y + c1.y;
            float ox = c0.x - c1.x, oy = c0.y - c1.y;
            float rx = ox * w.x - oy * wy;
            float ry = ox * wy + oy * w.x;
            int wi = 2 * p + k;
            fb[d][wi]     = make_float2(ex, ey);
            fb[d][wi + m] = make_float2(rx, ry);
        }
        m <<= 1;
        int tmp = s; s = d; d = tmp;
        __syncthreads();
    }
    return s;
}

// psi[b,t,:] = Re(IDFT(DFT(Q_sketch) * DFT(K_prefix))) / (N^1.5 * sqrt(t+1)) -> bf16
__global__ __launch_bounds__(256) void psi_fft_kernel(const float* __restrict__ qkv,
                                                      const float* __restrict__ sign,
                                                      const float* __restrict__ scal,
                                                      const int* __restrict__ h,
                                                      const float* __restrict__ KP,
                                                      bf16* __restrict__ psi_b) {
    __shared__ float2 fb[3][FFT_N];
    __shared__ float2 tw[FFT_N / 2];
    int bt = blockIdx.x;
    int tid = threadIdx.x;
    int t = bt & 127;

    for (int p = tid; p < 1024; p += 256) {
        float a = (float)p * (3.14159265358979323846f / 1024.0f);
        float sv, cv;
        sincosf(a, &sv, &cv);
        tw[p] = make_float2(cv, -sv);
    }
    for (int j = tid; j < FFT_N; j += 256) {
        fb[1][j] = make_float2(0.f, 0.f);
        fb[0][j] = make_float2(KP[(long)bt * M_ + j],
                               KP[(long)BT_ * M_ + (long)bt * M_ + j]);
    }
    __syncthreads();
    {
        float thq = scal[0], omg = scal[2];
        float ft = (float)t;
        for (int i = tid; i < D_; i += 256) {
            float q = qkv[(long)bt * 1536 + i];
            float sg = sign[i];
            float sv, cv;
            sincosf(thq * q - omg * ft, &sv, &cv);
            int m = h[i];
            atomicAdd(&fb[1][m].x, q * cv * sg);
            atomicAdd(&fb[1][m].y, q * sv * sg);
        }
    }
    __syncthreads();
    int rk = fft_run<1>(fb, tw, 0, 2, tid);
    int rq = fft_run<1>(fb, tw, 1, 0, tid);
    for (int u = 0; u < 8; ++u) {
        int j = u * 256 + tid;
        float2 a = fb[rq][j];
        float2 b = fb[rk][j];
        fb[1][j] = make_float2(a.x * b.x - a.y * b.y, a.x * b.y + a.y * b.x);
    }
    __syncthreads();
    int ri = fft_run<-1>(fb, tw, 1, 0, tid);
    float scale = rsqrtf((float)(t + 1)) * (1.0f / 92681.900089f);
    for (int u = 0; u < 8; ++u) {
        int j = u * 256 + tid;
        psi_b[(long)bt * M_ + j] = __float2bfloat16(fb[ri][j].x * scale);
    }
}

// MFMA bf16 TN GEMM: C[M,N] = A[M,K] * Bt[N,K]^T. 64x64 tile, 4 waves.
// splitk: bz = batch*splitk + slice (only meaningful with FLAG_ATOMIC).
// FLAG_HFB: bz in [0,16) -> b=bz&7, c=bz>>3 for the fused Hf GEMM.
template<int FLAGS, int OUTB16>
__global__ __launch_bounds__(256) void gemm_mfma(
    const bf16* __restrict__ A, const bf16* __restrict__ Bt,
    const float* __restrict__ bias, void* __restrict__ Cv,
    int K, int ldc, long abz, long bbz, long cbz, int splitk)
{
    __shared__ __align__(16) bf16 As[64][44];
    __shared__ __align__(16) bf16 Bs[64][44];
    int bz = blockIdx.z;
    int batch = bz, kslice = 0;
    if (FLAGS & FLAG_ATOMIC) { batch = bz / splitk; kslice = bz % splitk; }
    const bf16* Ab;
    const bf16* Bb;
    long coff;
    if (FLAGS & FLAG_HFB) {
        int b = bz & 7, c = bz >> 3;
        Ab = A + (long)b * abz + (long)blockIdx.y * 64 * K;
        Bb = Bt + (long)c * 2097152L + (long)b * 262144L + (long)blockIdx.x * 64 * K;
        coff = (long)b * 2097152L + (long)c * 1048576L;
    } else {
        Ab = A + (long)batch * abz + (long)blockIdx.y * 64 * K;
        Bb = Bt + (long)batch * bbz + (long)blockIdx.x * 64 * K;
        coff = (long)batch * cbz;
    }
    int tid = threadIdx.x;
    int lrow = tid >> 2;
    int lk = (tid & 3) * 8;
    int w = tid >> 6, lane = tid & 63;
    int wr = (w >> 1) * 32, wc = (w & 1) * 32;
    int fm = lane & 15, fk = (lane >> 4) * 8;
    f32x4 acc00 = {0.f,0.f,0.f,0.f}, acc01 = acc00, acc10 = acc00, acc11 = acc00;

    int klen = K / splitk;
    int k0 = kslice * klen;
    for (int kt = k0; kt < k0 + klen; kt += 32) {
        *(float4*)&As[lrow][lk] = *(const float4*)&Ab[(long)lrow * K + kt + lk];
        *(float4*)&Bs[lrow][lk] = *(const float4*)&Bb[(long)lrow * K + kt + lk];
        __syncthreads();
        short8t a0 = *(const short8t*)&As[wr + fm][fk];
        short8t a1 = *(const short8t*)&As[wr + 16 + fm][fk];
        short8t b0 = *(const short8t*)&Bs[wc + fm][fk];
        short8t b1 = *(const short8t*)&Bs[wc + 16 + fm][fk];
        acc00 = __builtin_amdgcn_mfma_f32_16x16x32_bf16(a0, b0, acc00, 0, 0, 0);
        acc01 = __builtin_amdgcn_mfma_f32_16x16x32_bf16(a0, b1, acc01, 0, 0, 0);
        acc10 = __builtin_amdgcn_mfma_f32_16x16x32_bf16(a1, b0, acc10, 0, 0, 0);
        acc11 = __builtin_amdgcn_mfma_f32_16x16x32_bf16(a1, b1, acc11, 0, 0, 0);
        __syncthreads();
    }

    float* Cf = (float*)Cv;
    bf16* Cb = (bf16*)Cv;
    int row_base = blockIdx.y * 64 + wr + (lane >> 4) * 4;
    int col_base = blockIdx.x * 64 + wc + fm;
    #pragma unroll
    for (int fr = 0; fr < 2; ++fr) {
        #pragma unroll
        for (int fc = 0; fc < 2; ++fc) {
            const f32x4& a = fr == 0 ? (fc == 0 ? acc00 : acc01) : (fc == 0 ? acc10 : acc11);
            #pragma unroll
            for (int r = 0; r < 4; ++r) {
                int gi = row_base + fr * 16 + r;
                int gj = col_base + fc * 16;
                float v = a[r];
                long ci = coff + (long)gi * ldc + gj;
                if (FLAGS & FLAG_ATOMIC) {
                    atomicAdd(&Cf[ci], v);
                } else {
                    if (FLAGS & FLAG_BIAS) v += bias[gj];
                    if (FLAGS & FLAG_GELU) v = gelu_f(v);
                    if (FLAGS & FLAG_ROWSCALE) v *= rsqrtf((float)(gi & 127) + 1.0f);
                    if (FLAGS & FLAG_MASK) { if (gj >= gi) v = 0.f; }
                    if (OUTB16) Cb[ci] = __float2bfloat16(v);
                    else        Cf[ci] = v;
                }
            }
        }
    }
}

// scores epilogue: mask upper triangle (tau >= t) and cast to bf16
__global__ __launch_bounds__(256) void scomask_kernel(const float* __restrict__ acc,
                                                      bf16* __restrict__ scob) {
    int idx = blockIdx.x * 256 + threadIdx.x;   // 8*128*128
    int t = (idx >> 7) & 127, tau = idx & 127;
    float v = (tau < t) ? acc[idx] : 0.f;
    scob[idx] = __float2bfloat16(v);
}

// LN over D=512. FINAL=0: LN(x1); FINAL=1: LN(x1 + gf*x2 + gv*x3). OB16 selects out dtype.
template<int FINAL, int OB16>
__global__ __launch_bounds__(256) void ln_kernel(const float* __restrict__ x1,
                                                 const float* __restrict__ x2,
                                                 const float* __restrict__ x3,
                                                 const float* __restrict__ g,
                                                 const float* __restrict__ bb,
                                                 const float* __restrict__ scal,
                                                 void* __restrict__ outv) {
    int row = blockIdx.x, tid = threadIdx.x;
    long base = (long)row * D_;
    int d0 = tid, d1 = tid + 256;
    float v0, v1;
    if (FINAL) {
        float gf = scal[3], gv = scal[4];
        v0 = x1[base + d0] + gf * x2[base + d0] + gv * x3[base + d0];
        v1 = x1[base + d1] + gf * x2[base + d1] + gv * x3[base + d1];
    } else {
        v0 = x1[base + d0];
        v1 = x1[base + d1];
    }
    float s = v0 + v1;
    #pragma unroll
    for (int o = 32; o > 0; o >>= 1) s += __shfl_down(s, o);
    __shared__ float red[8];
    int wid = tid >> 6, lane = tid & 63;
    if (lane == 0) red[wid] = s;
    __syncthreads();
    float mu = (red[0] + red[1] + red[2] + red[3]) * (1.0f / D_);
    float e0 = v0 - mu, e1 = v1 - mu;
    float sq = e0 * e0 + e1 * e1;
    #pragma unroll
    for (int o = 32; o > 0; o >>= 1) sq += __shfl_down(sq, o);
    if (lane == 0) red[4 + wid] = sq;
    __syncthreads();
    float var = (red[4] + red[5] + red[6] + red[7]) * (1.0f / D_);
    float rs = rsqrtf(var + 1e-5f);
    float o0 = e0 * rs * g[d0] + bb[d0];
    float o1 = e1 * rs * g[d1] + bb[d1];
    if (OB16) {
        ((bf16*)outv)[base + d0] = __float2bfloat16(o0);
        ((bf16*)outv)[base + d1] = __float2bfloat16(o1);
    } else {
        ((float*)outv)[base + d0] = o0;
        ((float*)outv)[base + d1] = o1;
    }
}

extern "C" void kernel_launch(void* const* d_in, const int* in_sizes, int n_in,
                              void* d_out, int out_size, void* d_ws, size_t ws_size,
                              hipStream_t stream) {
    const float* e      = (const float*)d_in[0];
    const int*   h      = (const int*)d_in[1];
    const float* sign   = (const float*)d_in[2];
    const float* Wq     = (const float*)d_in[3];
    const float* Wk     = (const float*)d_in[4];
    const float* Wv     = (const float*)d_in[5];
    const float* ro_w1  = (const float*)d_in[6];
    const float* ro_b1  = (const float*)d_in[7];
    const float* ro_w2  = (const float*)d_in[8];
    const float* ro_b2  = (const float*)d_in[9];
    const float* vp_ln_g= (const float*)d_in[10];
    const float* vp_ln_b= (const float*)d_in[11];
    const float* vp_w1  = (const float*)d_in[12];
    const float* vp_b1  = (const float*)d_in[13];
    const float* vp_w2  = (const float*)d_in[14];
    const float* vp_b2  = (const float*)d_in[15];
    const float* ln_g   = (const float*)d_in[16];
    const float* ln_b   = (const float*)d_in[17];
    const float* tq     = (const float*)d_in[18];
    const float* tk     = (const float*)d_in[19];
    const float* om     = (const float*)d_in[20];
    const float* gfr    = (const float*)d_in[21];
    const float* gvr    = (const float*)d_in[22];

    float* ws    = (float*)d_ws;
    float* scal  = ws + OFF_SCAL;
    float* qkv   = ws + OFF_QKV;
    float* sk2   = ws + OFF_SK2;
    float* kp    = ws + OFF_KP;
    float* vraw  = ws + OFF_VRAW;
    float* vf    = ws + OFF_VF;
    float* hfeat = ws + OFF_HFEAT;
    float* scoacc= ws + OFF_SCOA;
    bf16* eb    = (bf16*)(ws + OFF_EB);
    bf16* wqkvT = (bf16*)(ws + OFF_WQKVT);
    bf16* vp1T  = (bf16*)(ws + OFF_VP1T);
    bf16* vp2T  = (bf16*)(ws + OFF_VP2T);
    bf16* ro1T  = (bf16*)(ws + OFF_RO1T);
    bf16* ro2T  = (bf16*)(ws + OFF_RO2T);
    bf16* qcat  = (bf16*)(ws + OFF_QCAT);
    bf16* kcat  = (bf16*)(ws + OFF_KCAT);
    bf16* dkT   = (bf16*)(ws + OFF_DKT);
    bf16* vTb   = (bf16*)(ws + OFF_VTB);
    bf16* psib  = (bf16*)(ws + OFF_PSIB);
    bf16* scob  = (bf16*)(ws + OFF_SCOB);
    bf16* vlnb  = (bf16*)(ws + OFF_VLNB);
    bf16* v1b   = (bf16*)(ws + OFF_V1B);
    bf16* hidb  = (bf16*)(ws + OFF_HIDB);

    float* ys = (float*)d_out;
    float* kf = ys + (long)BT_ * D_;
    float* hf = kf + (long)B_ * 2 * M_;

    scal_kernel<<<1, 64, 0, stream>>>(tq, tk, om, gfr, gvr, scal);
    hipMemsetAsync(scoacc, 0, (size_t)B_ * T_ * T_ * 4, stream);

    // bf16 operand prep
    cast_kernel<<<2048, 256, 0, stream>>>(e, eb, BT_ * D_);
    castT5_kernel<<<dim3(16, 16, 5), 256, 0, stream>>>(
        Wq, Wk, Wv, vp_w1, vp_w2,
        wqkvT, wqkvT + 262144, wqkvT + 524288, vp1T, vp2T);
    castT_kernel<<<dim3(4, 64, 1), 256, 0, stream>>>(ro_w1, ro1T, 2048, 128, 128, 0, 0);
    castT_kernel<<<dim3(16, 4, 1), 256, 0, stream>>>(ro_w2, ro2T,  128, 512, 512, 0, 0);

    // qkv = e @ [Wq|Wk|Wv]  (1024 x 1536 x 512) -> f32
    gemm_mfma<0, 0><<<dim3(24, 16, 1), 256, 0, stream>>>(
        eb, wqkvT, nullptr, qkv, 512, 1536, 0, 0, 0, 1);

    sketch_kernel<<<1024, 256, 0, stream>>>(qkv, sign, scal, h, sk2, qcat, kcat);
    prefix_kernel<<<128, 256, 0, stream>>>(sk2, kp, kf);

    // psi via 3x 2048-pt FFT per (b,t)
    psi_fft_kernel<<<1024, 256, 0, stream>>>(qkv, sign, scal, h, kp, psib);

    // transposed bf16 copies (fused: z = comp*8 + b works because comp stride = 8*b stride)
    castT_kernel<<<dim3(64, 4, 16), 256, 0, stream>>>(sk2, dkT, 128, 2048, 2048, 262144, 262144);
    castT_kernel<<<dim3(16, 4, 8), 256, 0, stream>>>(qkv + 1024, vTb, 128, 512, 1536, 196608, 65536);

    // scores: split-K 16, f32 atomic accumulate (grid 2x2x128 = 512 blocks)
    gemm_mfma<FLAG_ATOMIC, 0><<<dim3(2, 2, 128), 256, 0, stream>>>(
        qcat, kcat, nullptr, scoacc, 4096, 128, 524288, 524288, 16384, 16);
    scomask_kernel<<<512, 256, 0, stream>>>(scoacc, scob);

    // vraw[b] = scores @ v * rsqrt(t+1)  (128x512x128) -> f32
    gemm_mfma<FLAG_ROWSCALE, 0><<<dim3(8, 2, 8), 256, 0, stream>>>(
        scob, vTb, nullptr, vraw, 128, 512, 16384, 65536, 65536, 1);

    ln_kernel<0, 1><<<1024, 256, 0, stream>>>(vraw, nullptr, nullptr, vp_ln_g, vp_ln_b, scal, vlnb);

    // vp MLP
    gemm_mfma<FLAG_BIAS | FLAG_GELU, 1><<<dim3(8, 16, 1), 256, 0, stream>>>(
        vlnb, vp1T, vp_b1, v1b, 512, 512, 0, 0, 0, 1);
    gemm_mfma<FLAG_BIAS, 0><<<dim3(8, 16, 1), 256, 0, stream>>>(
        v1b, vp2T, vp_b2, vf, 512, 512, 0, 0, 0, 1);

    // hid = gelu(psi @ ro_w1 + b1) (1024x128x2048) -> bf16
    gemm_mfma<FLAG_BIAS | FLAG_GELU, 1><<<dim3(2, 16, 1), 256, 0, stream>>>(
        psib, ro1T, ro_b1, hidb, 2048, 128, 0, 0, 0, 1);
    // hfeat = hid @ ro_w2 + b2 (1024x512x128)
    gemm_mfma<FLAG_BIAS, 0><<<dim3(8, 16, 1), 256, 0, stream>>>(
        hidb, ro2T, ro_b2, hfeat, 128, 512, 0, 0, 0, 1);

    // ys = LN(e + gf*hfeat + gv*vf)
    ln_kernel<1, 0><<<1024, 256, 0, stream>>>(e, hfeat, vf, ln_g, ln_b, scal, ys);

    // Hf fused: z in [0,16), b=z&7, c=z>>3
    gemm_mfma<FLAG_HFB, 0><<<dim3(32, 8, 16), 256, 0, stream>>>(
        vTb, dkT, nullptr, hf, 128, 2048, 65536, 0, 0, 1);
}

// Round 5
// 198.033 us; speedup vs baseline: 3.5812x; 1.0862x over previous
//
#include <hip/hip_runtime.h>
#include <hip/hip_bf16.h>
#include <math.h>

#define B_   8
#define T_   128
#define D_   512
#define M_   2048
#define HID_ 128
#define BT_  1024

typedef __attribute__((ext_vector_type(8))) short short8t;
typedef __attribute__((ext_vector_type(4))) float f32x4;
typedef __hip_bfloat16 bf16;

// ws layout (float offsets; all multiples of 16 -> 64B aligned)
#define OFF_SCAL   0L
#define OFF_QKV    16L                            // 1024*1536 f32
#define OFF_SK2    (OFF_QKV + 1572864L)           // [dKre|dKim] f32, 2*BT*M
#define OFF_KP     (OFF_SK2 + 4194304L)           // [KR|KI] f32 exclusive prefix
#define OFF_VRAW   (OFF_KP + 4194304L)
#define OFF_VF     (OFF_VRAW + 524288L)
#define OFF_HFEAT  (OFF_VF + 524288L)
// bf16 buffers (size in floats = elems/2)
#define OFF_EB     (OFF_HFEAT + 524288L)          // 1024x512
#define OFF_WQKVT  (OFF_EB + 262144L)             // 1536x512
#define OFF_VP1T   (OFF_WQKVT + 393216L)          // 512x512
#define OFF_VP2T   (OFF_VP1T + 131072L)
#define OFF_RO1T   (OFF_VP2T + 131072L)           // 128x2048
#define OFF_RO2T   (OFF_RO1T + 131072L)           // 512x128
#define OFF_QCAT   (OFF_RO2T + 32768L)            // 1024x4096
#define OFF_KCAT   (OFF_QCAT + 2097152L)          // 1024x4096
#define OFF_DKT    (OFF_KCAT + 2097152L)          // 2x8x2048x128
#define OFF_VTB    (OFF_DKT + 2097152L)           // 8x512x128
#define OFF_PSIB   (OFF_VTB + 262144L)            // 1024x2048
#define OFF_SCOB   (OFF_PSIB + 1048576L)          // 8x128x128 bf16
#define OFF_VLNB   (OFF_SCOB + 65536L)            // 1024x512
#define OFF_V1B    (OFF_VLNB + 262144L)           // 1024x512
#define OFF_HIDB   (OFF_V1B + 262144L)            // 1024x128
#define OFF_SCOA   (OFF_HIDB + 65536L)            // 8x128x128 f32 split-K accumulator
#define OFF_QSUM   (OFF_SCOA + 131072L)           // 4x32768 f32 prefix quarter sums

#define FLAG_BIAS     1
#define FLAG_GELU     2
#define FLAG_ROWSCALE 4
#define FLAG_ATOMIC   8
#define FLAG_MASK     16
#define FLAG_HFB      32

__device__ __forceinline__ float gelu_f(float x) {
    return 0.5f * x * (1.0f + erff(x * 0.70710678118654752440f));
}

__global__ void scal_kernel(const float* tq, const float* tk, const float* om,
                            const float* gf, const float* gv, float* scal) {
    if (threadIdx.x == 0) {
        scal[0] = 0.5f * tanhf(tq[0]);
        scal[1] = 0.5f * tanhf(tk[0]);
        scal[2] = 0.5f * tanhf(om[0]);
        scal[3] = 0.25f / (1.0f + expf(-gf[0]));
        scal[4] = 0.25f / (1.0f + expf(-gv[0]));
    }
}

__global__ __launch_bounds__(256) void cast_kernel(const float* __restrict__ in,
                                                   bf16* __restrict__ out, int n) {
    int i = blockIdx.x * 256 + threadIdx.x;
    if (i < n) out[i] = __float2bfloat16(in[i]);
}

// tiled transpose-cast: in f32 [R][C] (ld_in, batch bs_in) -> out bf16 [C][R] (batch bs_out)
__global__ __launch_bounds__(256) void castT_kernel(const float* __restrict__ in,
                                                    bf16* __restrict__ out,
                                                    int R, int C, int ld_in,
                                                    long bs_in, long bs_out) {
    __shared__ float tile[32][33];
    int b = blockIdx.z;
    int c0 = blockIdx.x * 32, r0 = blockIdx.y * 32;
    int tx = threadIdx.x & 31, ty = threadIdx.x >> 5;
    for (int rr = ty; rr < 32; rr += 8) {
        int r = r0 + rr, c = c0 + tx;
        tile[rr][tx] = (r < R && c < C) ? in[(long)b * bs_in + (long)r * ld_in + c] : 0.f;
    }
    __syncthreads();
    for (int cc = ty; cc < 32; cc += 8) {
        int c = c0 + cc, r = r0 + tx;
        if (c < C && r < R) out[(long)b * bs_out + (long)c * R + r] = __float2bfloat16(tile[tx][cc]);
    }
}

// batched 512x512 transpose-cast for 5 weights in one launch
__global__ __launch_bounds__(256) void castT5_kernel(const float* w0, const float* w1,
                                                     const float* w2, const float* w3,
                                                     const float* w4,
                                                     bf16* d0, bf16* d1, bf16* d2,
                                                     bf16* d3, bf16* d4) {
    __shared__ float tile[32][33];
    int z = blockIdx.z;
    const float* src; bf16* dst;
    if (z == 0)      { src = w0; dst = d0; }
    else if (z == 1) { src = w1; dst = d1; }
    else if (z == 2) { src = w2; dst = d2; }
    else if (z == 3) { src = w3; dst = d3; }
    else             { src = w4; dst = d4; }
    int c0 = blockIdx.x * 32, r0 = blockIdx.y * 32;
    int tx = threadIdx.x & 31, ty = threadIdx.x >> 5;
    for (int rr = ty; rr < 32; rr += 8)
        tile[rr][tx] = src[(long)(r0 + rr) * 512 + c0 + tx];
    __syncthreads();
    for (int cc = ty; cc < 32; cc += 8)
        dst[(long)(c0 + cc) * 512 + r0 + tx] = __float2bfloat16(tile[tx][cc]);
}

// sketch (phase fused): SK2 f32 = [dKre|dKim]; qcat bf16 = [Qre|Qim]; kcat bf16 = [dKre|-dKim]
__global__ __launch_bounds__(256) void sketch_kernel(const float* __restrict__ qkv,
                                                     const float* __restrict__ sign,
                                                     const float* __restrict__ scal,
                                                     const int* __restrict__ h,
                                                     float* __restrict__ SK2,
                                                     bf16* __restrict__ qcat,
                                                     bf16* __restrict__ kcat) {
    int bt = blockIdx.x;
    int tid = threadIdx.x;
    __shared__ float s0[M_], s1[M_], s2[M_], s3[M_];
    for (int j = tid; j < M_; j += 256) { s0[j] = 0.f; s1[j] = 0.f; s2[j] = 0.f; s3[j] = 0.f; }
    __syncthreads();
    int t = bt & 127;
    float thq = scal[0], thk = scal[1], omg = scal[2];
    float ft = (float)t;
    for (int i = tid; i < D_; i += 256) {
        float q = qkv[(long)bt * 1536 + i];
        float k = qkv[(long)bt * 1536 + 512 + i];
        float sg = sign[i];
        float sq_, cq_, sk_, ck_;
        sincosf(thq * q - omg * ft, &sq_, &cq_);
        sincosf(thk * k + omg * ft, &sk_, &ck_);
        int m = h[i];
        atomicAdd(&s0[m], q * cq_ * sg);
        atomicAdd(&s1[m], q * sq_ * sg);
        atomicAdd(&s2[m], k * ck_ * sg);
        atomicAdd(&s3[m], k * sk_ * sg);
    }
    __syncthreads();
    long ob = (long)bt * M_;
    long qb = (long)bt * 4096;
    for (int j = tid; j < M_; j += 256) {
        SK2[ob + j]                  = s2[j];
        SK2[(long)BT_ * M_ + ob + j] = s3[j];
        qcat[qb + j]        = __float2bfloat16(s0[j]);
        qcat[qb + 2048 + j] = __float2bfloat16(s1[j]);
        kcat[qb + j]        = __float2bfloat16(s2[j]);
        kcat[qb + 2048 + j] = __float2bfloat16(-s3[j]);
    }
}

// ---- two-phase exclusive prefix over t (4-way t split) ----
// col = comp*16384 + b*2048 + m   (32768 cols), q = t-quarter
__global__ __launch_bounds__(256) void prefix_p1(const float* __restrict__ SK2,
                                                 float* __restrict__ qsum) {
    int idx = blockIdx.x * 256 + threadIdx.x;   // 131072
    int col = idx & 32767, q = idx >> 15;
    int m = col & 2047, b = (col >> 11) & 7, comp = col >> 14;
    const float* src = SK2 + (long)comp * BT_ * M_ + (long)b * T_ * M_ + (long)(q * 32) * M_ + m;
    float s = 0.f;
    #pragma unroll 8
    for (int i = 0; i < 32; ++i) s += src[(long)i * M_];
    qsum[(long)q * 32768 + col] = s;
}

__global__ __launch_bounds__(256) void prefix_p2(const float* __restrict__ SK2,
                                                 const float* __restrict__ qsum,
                                                 float* __restrict__ KP,
                                                 float* __restrict__ kf_out) {
    int idx = blockIdx.x * 256 + threadIdx.x;   // 131072
    int col = idx & 32767, q = idx >> 15;
    int m = col & 2047, b = (col >> 11) & 7, comp = col >> 14;
    long cb = (long)comp * BT_ * M_ + (long)b * T_ * M_ + m + (long)(q * 32) * M_;
    const float* src = SK2 + cb;
    float* dst = KP + cb;
    float acc = 0.f;
    for (int p = 0; p < q; ++p) acc += qsum[(long)p * 32768 + col];
    #pragma unroll 4
    for (int i = 0; i < 32; ++i) {
        dst[(long)i * M_] = acc;
        acc += src[(long)i * M_];
    }
    if (q == 3) kf_out[((long)b * 2 + comp) * M_ + m] = acc;
}

// ---- 2048-pt FFT: in-place radix-2 + 5x radix-4 DIF, padded SoA LDS ----
#define PIDX(i) ((i) + ((i) >> 5))

__device__ __forceinline__ void cmul_ip(float& ar, float& ai, float br, float bi) {
    float r = ar * br - ai * bi;
    ai = ar * bi + ai * br;
    ar = r;
}

__device__ __forceinline__ void r4_fwd(float* re, float* im, int base, int m,
                                       float c1, float s1) {
    int i0 = PIDX(base), i1 = PIDX(base + m), i2 = PIDX(base + 2 * m), i3 = PIDX(base + 3 * m);
    float x0r = re[i0], x0i = im[i0], x1r = re[i1], x1i = im[i1];
    float x2r = re[i2], x2i = im[i2], x3r = re[i3], x3i = im[i3];
    float t0r = x0r + x2r, t0i = x0i + x2i;
    float t1r = x1r + x3r, t1i = x1i + x3i;
    float t2r = x0r - x2r, t2i = x0i - x2i;
    float ur  = x1r - x3r, ui  = x1i - x3i;
    float r0r = t0r + t1r, r0i = t0i + t1i;
    float r1r = t2r + ui,  r1i = t2i - ur;    // t2 - i*u
    float r2r = t0r - t1r, r2i = t0i - t1i;
    float r3r = t2r - ui,  r3i = t2i + ur;    // t2 + i*u
    float c2 = c1 * c1 - s1 * s1, s2 = 2.f * c1 * s1;
    float c3 = c2 * c1 - s2 * s1, s3 = c2 * s1 + s2 * c1;
    cmul_ip(r1r, r1i, c1, s1);
    cmul_ip(r2r, r2i, c2, s2);
    cmul_ip(r3r, r3i, c3, s3);
    re[i0] = r0r; im[i0] = r0i;
    re[i1] = r1r; im[i1] = r1i;
    re[i2] = r2r; im[i2] = r2i;
    re[i3] = r3r; im[i3] = r3i;
}

__device__ __forceinline__ void r4_inv(float* re, float* im, int base, int m,
                                       float c1, float s1) {
    int i0 = PIDX(base), i1 = PIDX(base + m), i2 = PIDX(base + 2 * m), i3 = PIDX(base + 3 * m);
    float y0r = re[i0], y0i = im[i0];
    float z1r = re[i1], z1i = im[i1];
    float z2r = re[i2], z2i = im[i2];
    float z3r = re[i3], z3i = im[i3];
    float c2 = c1 * c1 - s1 * s1, s2 = 2.f * c1 * s1;
    float c3 = c2 * c1 - s2 * s1, s3 = c2 * s1 + s2 * c1;
    cmul_ip(z1r, z1i, c1, -s1);
    cmul_ip(z2r, z2i, c2, -s2);
    cmul_ip(z3r, z3i, c3, -s3);
    float ar  = z1r - z3r, ai_ = z1i - z3i;   // z1 - z3
    float sr  = z1r + z3r, si  = z1i + z3i;   // z1 + z3
    float e0r = y0r + z2r, e0i = y0i + z2i;
    float e1r = y0r - z2r, e1i = y0i - z2i;
    re[i0] = e0r + sr;  im[i0] = e0i + si;    // y0+z1+z2+z3
    re[i1] = e1r - ai_; im[i1] = e1i + ar;    // + i(z1-z3)
    re[i2] = e0r - sr;  im[i2] = e0i - si;
    re[i3] = e1r + ai_; im[i3] = e1i - ar;    // - i(z1-z3)
}

template<int M>
__device__ __forceinline__ void fwd_stage2(float* kr, float* ki, float* qr, float* qi, int tid) {
    const float angu = -6.2831853071795864769f / (4.0f * (float)M);
    #pragma unroll
    for (int u = 0; u < 2; ++u) {
        int b = u * 256 + tid;
        int blk = b / M;
        int j = b - blk * M;
        int base = blk * 4 * M + j;
        float s, c;
        sincosf((float)j * angu, &s, &c);
        r4_fwd(kr, ki, base, M, c, s);
        r4_fwd(qr, qi, base, M, c, s);
    }
}

template<int M>
__device__ __forceinline__ void inv_stage1(float* re, float* im, int tid) {
    const float angu = -6.2831853071795864769f / (4.0f * (float)M);
    #pragma unroll
    for (int u = 0; u < 2; ++u) {
        int b = u * 256 + tid;
        int blk = b / M;
        int j = b - blk * M;
        int base = blk * 4 * M + j;
        float s, c;
        sincosf((float)j * angu, &s, &c);
        r4_inv(re, im, base, M, c, s);
    }
}

__device__ __forceinline__ void r2_fwd_stage(float* kr, float* ki, float* qr, float* qi, int tid) {
    #pragma unroll
    for (int u = 0; u < 4; ++u) {
        int j = u * 256 + tid;
        float s, c;
        sincosf((float)j * (-6.2831853071795864769f / 2048.0f), &s, &c);
        int i0 = PIDX(j), i1 = PIDX(j + 1024);
        {
            float ar = kr[i0], ai = ki[i0], br = kr[i1], bi = ki[i1];
            kr[i0] = ar + br; ki[i0] = ai + bi;
            float dr = ar - br, di = ai - bi;
            kr[i1] = dr * c - di * s; ki[i1] = dr * s + di * c;
        }
        {
            float ar = qr[i0], ai = qi[i0], br = qr[i1], bi = qi[i1];
            qr[i0] = ar + br; qi[i0] = ai + bi;
            float dr = ar - br, di = ai - bi;
            qr[i1] = dr * c - di * s; qi[i1] = dr * s + di * c;
        }
    }
}

__device__ __forceinline__ void r2_inv_stage(float* re, float* im, int tid) {
    #pragma unroll
    for (int u = 0; u < 4; ++u) {
        int j = u * 256 + tid;
        float s, c;
        sincosf((float)j * (-6.2831853071795864769f / 2048.0f), &s, &c);
        int i0 = PIDX(j), i1 = PIDX(j + 1024);
        float pr = re[i0], pi_ = im[i0];
        float br = re[i1], bi = im[i1];
        float zr = br * c + bi * s;     // b * conj(w)
        float zi = bi * c - br * s;
        re[i0] = pr + zr; im[i0] = pi_ + zi;
        re[i1] = pr - zr; im[i1] = pi_ - zi;
    }
}

// psi[b,t,:] = Re(conv) / (N^1.5-equivalent scale) -> bf16
__global__ __launch_bounds__(256) void psi_fft_kernel(const float* __restrict__ qkv,
                                                      const float* __restrict__ sign,
                                                      const float* __restrict__ scal,
                                                      const int* __restrict__ h,
                                                      const float* __restrict__ KP,
                                                      bf16* __restrict__ psi_b) {
    __shared__ float kr[2112], ki[2112], qr[2112], qi[2112];   // 33 KB
    int bt = blockIdx.x, tid = threadIdx.x, t = bt & 127;

    for (int u = 0; u < 8; ++u) {
        int j = u * 256 + tid;
        int pj = PIDX(j);
        kr[pj] = KP[(long)bt * M_ + j];
        ki[pj] = KP[(long)BT_ * M_ + (long)bt * M_ + j];
        qr[pj] = 0.f; qi[pj] = 0.f;
    }
    __syncthreads();
    {
        float thq = scal[0], omg = scal[2];
        float ft = (float)t;
        for (int i = tid; i < D_; i += 256) {
            float q = qkv[(long)bt * 1536 + i];
            float sg = sign[i];
            float sv, cv;
            sincosf(thq * q - omg * ft, &sv, &cv);
            int pm = PIDX(h[i]);
            atomicAdd(&qr[pm], q * cv * sg);
            atomicAdd(&qi[pm], q * sv * sg);
        }
    }
    __syncthreads();
    r2_fwd_stage(kr, ki, qr, qi, tid);   __syncthreads();
    fwd_stage2<256>(kr, ki, qr, qi, tid); __syncthreads();
    fwd_stage2<64>(kr, ki, qr, qi, tid);  __syncthreads();
    fwd_stage2<16>(kr, ki, qr, qi, tid);  __syncthreads();
    fwd_stage2<4>(kr, ki, qr, qi, tid);   __syncthreads();
    fwd_stage2<1>(kr, ki, qr, qi, tid);   __syncthreads();
    for (int u = 0; u < 8; ++u) {
        int j = PIDX(u * 256 + tid);
        float ar = qr[j], ai = qi[j], br = kr[j], bi = ki[j];
        qr[j] = ar * br - ai * bi;
        qi[j] = ar * bi + ai * br;
    }
    __syncthreads();
    inv_stage1<1>(qr, qi, tid);   __syncthreads();
    inv_stage1<4>(qr, qi, tid);   __syncthreads();
    inv_stage1<16>(qr, qi, tid);  __syncthreads();
    inv_stage1<64>(qr, qi, tid);  __syncthreads();
    inv_stage1<256>(qr, qi, tid); __syncthreads();
    r2_inv_stage(qr, qi, tid);    __syncthreads();
    float scale = rsqrtf((float)(t + 1)) * (1.0f / 92681.900089f);   // 1/2048^1.5
    for (int u = 0; u < 8; ++u) {
        int j = u * 256 + tid;
        psi_b[(long)bt * M_ + j] = __float2bfloat16(qr[PIDX(j)] * scale);
    }
}

// MFMA bf16 TN GEMM: C[M,N] = A[M,K] * Bt[N,K]^T. 64x64 tile, 4 waves.
template<int FLAGS, int OUTB16>
__global__ __launch_bounds__(256) void gemm_mfma(
    const bf16* __restrict__ A, const bf16* __restrict__ Bt,
    const float* __restrict__ bias, void* __restrict__ Cv,
    int K, int ldc, long abz, long bbz, long cbz, int splitk)
{
    __shared__ __align__(16) bf16 As[64][44];
    __shared__ __align__(16) bf16 Bs[64][44];
    int bz = blockIdx.z;
    int batch = bz, kslice = 0;
    if (FLAGS & FLAG_ATOMIC) { batch = bz / splitk; kslice = bz % splitk; }
    const bf16* Ab;
    const bf16* Bb;
    long coff;
    if (FLAGS & FLAG_HFB) {
        int b = bz & 7, c = bz >> 3;
        Ab = A + (long)b * abz + (long)blockIdx.y * 64 * K;
        Bb = Bt + (long)c * 2097152L + (long)b * 262144L + (long)blockIdx.x * 64 * K;
        coff = (long)b * 2097152L + (long)c * 1048576L;
    } else {
        Ab = A + (long)batch * abz + (long)blockIdx.y * 64 * K;
        Bb = Bt + (long)batch * bbz + (long)blockIdx.x * 64 * K;
        coff = (long)batch * cbz;
    }
    int tid = threadIdx.x;
    int lrow = tid >> 2;
    int lk = (tid & 3) * 8;
    int w = tid >> 6, lane = tid & 63;
    int wr = (w >> 1) * 32, wc = (w & 1) * 32;
    int fm = lane & 15, fk = (lane >> 4) * 8;
    f32x4 acc00 = {0.f,0.f,0.f,0.f}, acc01 = acc00, acc10 = acc00, acc11 = acc00;

    int klen = K / splitk;
    int k0 = kslice * klen;
    for (int kt = k0; kt < k0 + klen; kt += 32) {
        *(float4*)&As[lrow][lk] = *(const float4*)&Ab[(long)lrow * K + kt + lk];
        *(float4*)&Bs[lrow][lk] = *(const float4*)&Bb[(long)lrow * K + kt + lk];
        __syncthreads();
        short8t a0 = *(const short8t*)&As[wr + fm][fk];
        short8t a1 = *(const short8t*)&As[wr + 16 + fm][fk];
        short8t b0 = *(const short8t*)&Bs[wc + fm][fk];
        short8t b1 = *(const short8t*)&Bs[wc + 16 + fm][fk];
        acc00 = __builtin_amdgcn_mfma_f32_16x16x32_bf16(a0, b0, acc00, 0, 0, 0);
        acc01 = __builtin_amdgcn_mfma_f32_16x16x32_bf16(a0, b1, acc01, 0, 0, 0);
        acc10 = __builtin_amdgcn_mfma_f32_16x16x32_bf16(a1, b0, acc10, 0, 0, 0);
        acc11 = __builtin_amdgcn_mfma_f32_16x16x32_bf16(a1, b1, acc11, 0, 0, 0);
        __syncthreads();
    }

    float* Cf = (float*)Cv;
    bf16* Cb = (bf16*)Cv;
    int row_base = blockIdx.y * 64 + wr + (lane >> 4) * 4;
    int col_base = blockIdx.x * 64 + wc + fm;
    #pragma unroll
    for (int fr = 0; fr < 2; ++fr) {
        #pragma unroll
        for (int fc = 0; fc < 2; ++fc) {
            const f32x4& a = fr == 0 ? (fc == 0 ? acc00 : acc01) : (fc == 0 ? acc10 : acc11);
            #pragma unroll
            for (int r = 0; r < 4; ++r) {
                int gi = row_base + fr * 16 + r;
                int gj = col_base + fc * 16;
                float v = a[r];
                long ci = coff + (long)gi * ldc + gj;
                if (FLAGS & FLAG_ATOMIC) {
                    atomicAdd(&Cf[ci], v);
                } else {
                    if (FLAGS & FLAG_BIAS) v += bias[gj];
                    if (FLAGS & FLAG_GELU) v = gelu_f(v);
                    if (FLAGS & FLAG_ROWSCALE) v *= rsqrtf((float)(gi & 127) + 1.0f);
                    if (FLAGS & FLAG_MASK) { if (gj >= gi) v = 0.f; }
                    if (OUTB16) Cb[ci] = __float2bfloat16(v);
                    else        Cf[ci] = v;
                }
            }
        }
    }
}

// scores epilogue: mask upper triangle (tau >= t) and cast to bf16
__global__ __launch_bounds__(256) void scomask_kernel(const float* __restrict__ acc,
                                                      bf16* __restrict__ scob) {
    int idx = blockIdx.x * 256 + threadIdx.x;   // 8*128*128
    int t = (idx >> 7) & 127, tau = idx & 127;
    float v = (tau < t) ? acc[idx] : 0.f;
    scob[idx] = __float2bfloat16(v);
}

// LN over D=512. FINAL=0: LN(x1); FINAL=1: LN(x1 + gf*x2 + gv*x3). OB16 selects out dtype.
template<int FINAL, int OB16>
__global__ __launch_bounds__(256) void ln_kernel(const float* __restrict__ x1,
                                                 const float* __restrict__ x2,
                                                 const float* __restrict__ x3,
                                                 const float* __restrict__ g,
                                                 const float* __restrict__ bb,
                                                 const float* __restrict__ scal,
                                                 void* __restrict__ outv) {
    int row = blockIdx.x, tid = threadIdx.x;
    long base = (long)row * D_;
    int d0 = tid, d1 = tid + 256;
    float v0, v1;
    if (FINAL) {
        float gf = scal[3], gv = scal[4];
        v0 = x1[base + d0] + gf * x2[base + d0] + gv * x3[base + d0];
        v1 = x1[base + d1] + gf * x2[base + d1] + gv * x3[base + d1];
    } else {
        v0 = x1[base + d0];
        v1 = x1[base + d1];
    }
    float s = v0 + v1;
    #pragma unroll
    for (int o = 32; o > 0; o >>= 1) s += __shfl_down(s, o);
    __shared__ float red[8];
    int wid = tid >> 6, lane = tid & 63;
    if (lane == 0) red[wid] = s;
    __syncthreads();
    float mu = (red[0] + red[1] + red[2] + red[3]) * (1.0f / D_);
    float e0 = v0 - mu, e1 = v1 - mu;
    float sq = e0 * e0 + e1 * e1;
    #pragma unroll
    for (int o = 32; o > 0; o >>= 1) sq += __shfl_down(sq, o);
    if (lane == 0) red[4 + wid] = sq;
    __syncthreads();
    float var = (red[4] + red[5] + red[6] + red[7]) * (1.0f / D_);
    float rs = rsqrtf(var + 1e-5f);
    float o0 = e0 * rs * g[d0] + bb[d0];
    float o1 = e1 * rs * g[d1] + bb[d1];
    if (OB16) {
        ((bf16*)outv)[base + d0] = __float2bfloat16(o0);
        ((bf16*)outv)[base + d1] = __float2bfloat16(o1);
    } else {
        ((float*)outv)[base + d0] = o0;
        ((float*)outv)[base + d1] = o1;
    }
}

extern "C" void kernel_launch(void* const* d_in, const int* in_sizes, int n_in,
                              void* d_out, int out_size, void* d_ws, size_t ws_size,
                              hipStream_t stream) {
    const float* e      = (const float*)d_in[0];
    const int*   h      = (const int*)d_in[1];
    const float* sign   = (const float*)d_in[2];
    const float* Wq     = (const float*)d_in[3];
    const float* Wk     = (const float*)d_in[4];
    const float* Wv     = (const float*)d_in[5];
    const float* ro_w1  = (const float*)d_in[6];
    const float* ro_b1  = (const float*)d_in[7];
    const float* ro_w2  = (const float*)d_in[8];
    const float* ro_b2  = (const float*)d_in[9];
    const float* vp_ln_g= (const float*)d_in[10];
    const float* vp_ln_b= (const float*)d_in[11];
    const float* vp_w1  = (const float*)d_in[12];
    const float* vp_b1  = (const float*)d_in[13];
    const float* vp_w2  = (const float*)d_in[14];
    const float* vp_b2  = (const float*)d_in[15];
    const float* ln_g   = (const float*)d_in[16];
    const float* ln_b   = (const float*)d_in[17];
    const float* tq     = (const float*)d_in[18];
    const float* tk     = (const float*)d_in[19];
    const float* om     = (const float*)d_in[20];
    const float* gfr    = (const float*)d_in[21];
    const float* gvr    = (const float*)d_in[22];

    float* ws    = (float*)d_ws;
    float* scal  = ws + OFF_SCAL;
    float* qkv   = ws + OFF_QKV;
    float* sk2   = ws + OFF_SK2;
    float* kp    = ws + OFF_KP;
    float* vraw  = ws + OFF_VRAW;
    float* vf    = ws + OFF_VF;
    float* hfeat = ws + OFF_HFEAT;
    float* scoacc= ws + OFF_SCOA;
    float* qsum  = ws + OFF_QSUM;
    bf16* eb    = (bf16*)(ws + OFF_EB);
    bf16* wqkvT = (bf16*)(ws + OFF_WQKVT);
    bf16* vp1T  = (bf16*)(ws + OFF_VP1T);
    bf16* vp2T  = (bf16*)(ws + OFF_VP2T);
    bf16* ro1T  = (bf16*)(ws + OFF_RO1T);
    bf16* ro2T  = (bf16*)(ws + OFF_RO2T);
    bf16* qcat  = (bf16*)(ws + OFF_QCAT);
    bf16* kcat  = (bf16*)(ws + OFF_KCAT);
    bf16* dkT   = (bf16*)(ws + OFF_DKT);
    bf16* vTb   = (bf16*)(ws + OFF_VTB);
    bf16* psib  = (bf16*)(ws + OFF_PSIB);
    bf16* scob  = (bf16*)(ws + OFF_SCOB);
    bf16* vlnb  = (bf16*)(ws + OFF_VLNB);
    bf16* v1b   = (bf16*)(ws + OFF_V1B);
    bf16* hidb  = (bf16*)(ws + OFF_HIDB);

    float* ys = (float*)d_out;
    float* kf = ys + (long)BT_ * D_;
    float* hf = kf + (long)B_ * 2 * M_;

    scal_kernel<<<1, 64, 0, stream>>>(tq, tk, om, gfr, gvr, scal);
    hipMemsetAsync(scoacc, 0, (size_t)B_ * T_ * T_ * 4, stream);

    // bf16 operand prep
    cast_kernel<<<2048, 256, 0, stream>>>(e, eb, BT_ * D_);
    castT5_kernel<<<dim3(16, 16, 5), 256, 0, stream>>>(
        Wq, Wk, Wv, vp_w1, vp_w2,
        wqkvT, wqkvT + 262144, wqkvT + 524288, vp1T, vp2T);
    castT_kernel<<<dim3(4, 64, 1), 256, 0, stream>>>(ro_w1, ro1T, 2048, 128, 128, 0, 0);
    castT_kernel<<<dim3(16, 4, 1), 256, 0, stream>>>(ro_w2, ro2T,  128, 512, 512, 0, 0);

    // qkv = e @ [Wq|Wk|Wv]  (1024 x 1536 x 512) -> f32
    gemm_mfma<0, 0><<<dim3(24, 16, 1), 256, 0, stream>>>(
        eb, wqkvT, nullptr, qkv, 512, 1536, 0, 0, 0, 1);

    sketch_kernel<<<1024, 256, 0, stream>>>(qkv, sign, scal, h, sk2, qcat, kcat);
    prefix_p1<<<512, 256, 0, stream>>>(sk2, qsum);
    prefix_p2<<<512, 256, 0, stream>>>(sk2, qsum, kp, kf);

    // psi via radix-4 in-place convolution FFT
    psi_fft_kernel<<<1024, 256, 0, stream>>>(qkv, sign, scal, h, kp, psib);

    // transposed bf16 copies (fused: z = comp*8 + b works because comp stride = 8*b stride)
    castT_kernel<<<dim3(64, 4, 16), 256, 0, stream>>>(sk2, dkT, 128, 2048, 2048, 262144, 262144);
    castT_kernel<<<dim3(16, 4, 8), 256, 0, stream>>>(qkv + 1024, vTb, 128, 512, 1536, 196608, 65536);

    // scores: split-K 16, f32 atomic accumulate (grid 2x2x128 = 512 blocks)
    gemm_mfma<FLAG_ATOMIC, 0><<<dim3(2, 2, 128), 256, 0, stream>>>(
        qcat, kcat, nullptr, scoacc, 4096, 128, 524288, 524288, 16384, 16);
    scomask_kernel<<<512, 256, 0, stream>>>(scoacc, scob);

    // vraw[b] = scores @ v * rsqrt(t+1)  (128x512x128) -> f32
    gemm_mfma<FLAG_ROWSCALE, 0><<<dim3(8, 2, 8), 256, 0, stream>>>(
        scob, vTb, nullptr, vraw, 128, 512, 16384, 65536, 65536, 1);

    ln_kernel<0, 1><<<1024, 256, 0, stream>>>(vraw, nullptr, nullptr, vp_ln_g, vp_ln_b, scal, vlnb);

    // vp MLP
    gemm_mfma<FLAG_BIAS | FLAG_GELU, 1><<<dim3(8, 16, 1), 256, 0, stream>>>(
        vlnb, vp1T, vp_b1, v1b, 512, 512, 0, 0, 0, 1);
    gemm_mfma<FLAG_BIAS, 0><<<dim3(8, 16, 1), 256, 0, stream>>>(
        v1b, vp2T, vp_b2, vf, 512, 512, 0, 0, 0, 1);

    // hid = gelu(psi @ ro_w1 + b1) (1024x128x2048) -> bf16
    gemm_mfma<FLAG_BIAS | FLAG_GELU, 1><<<dim3(2, 16, 1), 256, 0, stream>>>(
        psib, ro1T, ro_b1, hidb, 2048, 128, 0, 0, 0, 1);
    // hfeat = hid @ ro_w2 + b2 (1024x512x128)
    gemm_mfma<FLAG_BIAS, 0><<<dim3(8, 16, 1), 256, 0, stream>>>(
        hidb, ro2T, ro_b2, hfeat, 128, 512, 0, 0, 0, 1);

    // ys = LN(e + gf*hfeat + gv*vf)
    ln_kernel<1, 0><<<1024, 256, 0, stream>>>(e, hfeat, vf, ln_g, ln_b, scal, ys);

    // Hf fused: z in [0,16), b=z&7, c=z>>3
    gemm_mfma<FLAG_HFB, 0><<<dim3(32, 8, 16), 256, 0, stream>>>(
        vTb, dkT, nullptr, hf, 128, 2048, 65536, 0, 0, 1);
}